// Round 1
// baseline (10814.527 us; speedup 1.0000x reference)
//
#include <hip/hip_runtime.h>

#define D 128
#define NG 64
#define NL 3

constexpr int TILE_R = 32;
constexpr int LDSTR  = 132;   // padded row stride (floats), 16B-aligned

__device__ __forceinline__ float f4c(const float4& v, int i) {
  return i == 0 ? v.x : (i == 1 ? v.y : (i == 2 ? v.z : v.w));
}

// ---------------- degree ----------------
__global__ void k_deg(const int* __restrict__ dst, float* __restrict__ deg, int E) {
  int i = blockIdx.x * blockDim.x + threadIdx.x;
  int stride = gridDim.x * blockDim.x;
  for (; i < E; i += stride) atomicAdd(&deg[dst[i]], 1.0f);
}

__global__ void k_invdeg(float* __restrict__ deg, int n) {
  int i = blockIdx.x * blockDim.x + threadIdx.x;
  if (i < n) deg[i] = 1.0f / fmaxf(deg[i], 1.0f);
}

// ---------------- GEMM: H = A@Ws (+ (B*invdeg)@Wn) + bias ----------------
template <bool TWO>
__global__ __launch_bounds__(256, 2) void k_gemm(
    const float* __restrict__ A, const float* __restrict__ B,
    const float* __restrict__ invdeg,
    const float* __restrict__ Ws, const float* __restrict__ Wn,
    const float* __restrict__ bias, float* __restrict__ Hout, int n)
{
  __shared__ float a_lds[TILE_R][LDSTR];
  __shared__ float b_lds[TILE_R][LDSTR];
  __shared__ float ws_lds[32][D];
  __shared__ float wn_lds[32][D];

  const int tid  = threadIdx.x;
  const int tcol = tid & 31;    // 32 col-groups of 4
  const int trow = tid >> 5;    // 8 row-groups of 4
  const long base = (long)blockIdx.x * TILE_R;

  // stage A (and scaled B) tile: 32x128 floats, 4 float4 per thread
#pragma unroll
  for (int i = 0; i < 4; ++i) {
    int idx = tid + i * 256;
    int r   = idx >> 5;
    int c4  = (idx & 31) << 2;
    long rr = base + r;
    long rc = rr < n ? rr : (n - 1);
    float4 v = *(const float4*)&A[rc * D + c4];
    *(float4*)&a_lds[r][c4] = v;
    if (TWO) {
      float sc = invdeg[rc];
      float4 w = *(const float4*)&B[rc * D + c4];
      w.x *= sc; w.y *= sc; w.z *= sc; w.w *= sc;
      *(float4*)&b_lds[r][c4] = w;
    }
  }

  float acc[4][4] = {};

  for (int k0 = 0; k0 < D; k0 += 32) {
    __syncthreads();
#pragma unroll
    for (int i = 0; i < 4; ++i) {
      int idx = tid + i * 256;
      int r   = idx >> 5;
      int c4  = (idx & 31) << 2;
      *(float4*)&ws_lds[r][c4] = *(const float4*)&Ws[(long)(k0 + r) * D + c4];
      if (TWO)
        *(float4*)&wn_lds[r][c4] = *(const float4*)&Wn[(long)(k0 + r) * D + c4];
    }
    __syncthreads();

#pragma unroll
    for (int kc = 0; kc < 8; ++kc) {
      float4 a0 = *(const float4*)&a_lds[trow * 4 + 0][k0 + kc * 4];
      float4 a1 = *(const float4*)&a_lds[trow * 4 + 1][k0 + kc * 4];
      float4 a2 = *(const float4*)&a_lds[trow * 4 + 2][k0 + kc * 4];
      float4 a3 = *(const float4*)&a_lds[trow * 4 + 3][k0 + kc * 4];
      float4 b0, b1, b2, b3;
      if (TWO) {
        b0 = *(const float4*)&b_lds[trow * 4 + 0][k0 + kc * 4];
        b1 = *(const float4*)&b_lds[trow * 4 + 1][k0 + kc * 4];
        b2 = *(const float4*)&b_lds[trow * 4 + 2][k0 + kc * 4];
        b3 = *(const float4*)&b_lds[trow * 4 + 3][k0 + kc * 4];
      }
#pragma unroll
      for (int kk = 0; kk < 4; ++kk) {
        float4 ws = *(const float4*)&ws_lds[kc * 4 + kk][tcol * 4];
        float av0 = f4c(a0, kk), av1 = f4c(a1, kk), av2 = f4c(a2, kk), av3 = f4c(a3, kk);
        acc[0][0] += av0 * ws.x; acc[0][1] += av0 * ws.y; acc[0][2] += av0 * ws.z; acc[0][3] += av0 * ws.w;
        acc[1][0] += av1 * ws.x; acc[1][1] += av1 * ws.y; acc[1][2] += av1 * ws.z; acc[1][3] += av1 * ws.w;
        acc[2][0] += av2 * ws.x; acc[2][1] += av2 * ws.y; acc[2][2] += av2 * ws.z; acc[2][3] += av2 * ws.w;
        acc[3][0] += av3 * ws.x; acc[3][1] += av3 * ws.y; acc[3][2] += av3 * ws.z; acc[3][3] += av3 * ws.w;
        if (TWO) {
          float4 wn = *(const float4*)&wn_lds[kc * 4 + kk][tcol * 4];
          float bv0 = f4c(b0, kk), bv1 = f4c(b1, kk), bv2 = f4c(b2, kk), bv3 = f4c(b3, kk);
          acc[0][0] += bv0 * wn.x; acc[0][1] += bv0 * wn.y; acc[0][2] += bv0 * wn.z; acc[0][3] += bv0 * wn.w;
          acc[1][0] += bv1 * wn.x; acc[1][1] += bv1 * wn.y; acc[1][2] += bv1 * wn.z; acc[1][3] += bv1 * wn.w;
          acc[2][0] += bv2 * wn.x; acc[2][1] += bv2 * wn.y; acc[2][2] += bv2 * wn.z; acc[2][3] += bv2 * wn.w;
          acc[3][0] += bv3 * wn.x; acc[3][1] += bv3 * wn.y; acc[3][2] += bv3 * wn.z; acc[3][3] += bv3 * wn.w;
        }
      }
    }
  }

  float4 bs = *(const float4*)&bias[tcol * 4];
#pragma unroll
  for (int r = 0; r < 4; ++r) {
    long row = base + trow * 4 + r;
    if (row < n) {
      float4 o;
      o.x = acc[r][0] + bs.x; o.y = acc[r][1] + bs.y;
      o.z = acc[r][2] + bs.z; o.w = acc[r][3] + bs.w;
      *(float4*)&Hout[row * D + tcol * 4] = o;
    }
  }
}

// ---------------- edge scatter: agg[dst] += node[src] ----------------
__global__ void k_scatter(const float* __restrict__ node,
                          const int* __restrict__ src,
                          const int* __restrict__ dst,
                          float* __restrict__ agg, long total)
{
  long idx = (long)blockIdx.x * blockDim.x + threadIdx.x;
  long stride = (long)gridDim.x * blockDim.x;
  for (; idx < total; idx += stride) {
    int e = (int)(idx >> 5);
    int q = (int)(idx & 31) << 2;
    int s = src[e], t = dst[e];
    float4 v = *(const float4*)&node[(long)s * D + q];
    float* p = &agg[(long)t * D + q];
    atomicAdd(p + 0, v.x);
    atomicAdd(p + 1, v.y);
    atomicAdd(p + 2, v.z);
    atomicAdd(p + 3, v.w);
  }
}

// ---------------- graph segment sum (batch sorted) ----------------
__global__ void k_gsum(const float* __restrict__ h,
                       const int* __restrict__ batch,
                       float* __restrict__ gacc, int n)
{
  const int d = threadIdx.x;                // 128 threads, one per dim
  int r0 = blockIdx.x * 512;
  int r1 = min(n, r0 + 512);
  if (r0 >= n) return;
  float acc = 0.f;
  int cur = batch[r0];
  for (int r = r0; r < r1; ++r) {
    int b = batch[r];
    if (b != cur) { atomicAdd(&gacc[cur * D + d], acc); acc = 0.f; cur = b; }
    acc += h[(long)r * D + d];
  }
  atomicAdd(&gacc[cur * D + d], acc);
}

// ---------------- node LN: node = relu(LN(h + node)) ----------------
__global__ void k_ln_node(const float* __restrict__ h,
                          float* __restrict__ node,
                          const float* __restrict__ lg,
                          const float* __restrict__ lb, int n)
{
  int lane = threadIdx.x & 63;
  long wid = (((long)blockIdx.x * blockDim.x + threadIdx.x) >> 6);
  long nw  = (((long)gridDim.x * blockDim.x) >> 6);
  float2 gv = *(const float2*)&lg[lane * 2];
  float2 bv = *(const float2*)&lb[lane * 2];
  for (long r = wid; r < n; r += nw) {
    float2 hv = *(const float2*)&h[r * D + lane * 2];
    float2 nv = *(const float2*)&node[r * D + lane * 2];
    float x0 = hv.x + nv.x, x1 = hv.y + nv.y;
    float s = x0 + x1, q = x0 * x0 + x1 * x1;
#pragma unroll
    for (int m = 1; m < 64; m <<= 1) { s += __shfl_xor(s, m); q += __shfl_xor(q, m); }
    float mean = s * (1.f / 128.f);
    float var  = q * (1.f / 128.f) - mean * mean;
    float rs   = rsqrtf(fmaxf(var, 0.f) + 1e-5f);
    float y0 = (x0 - mean) * rs * gv.x + bv.x;
    float y1 = (x1 - mean) * rs * gv.y + bv.y;
    float2 o; o.x = fmaxf(y0, 0.f); o.y = fmaxf(y1, 0.f);
    *(float2*)&node[r * D + lane * 2] = o;
  }
}

// ---------------- graph LN: graph = LN(LN(gacc + graph)) ----------------
__global__ void k_ln_graph(const float* __restrict__ gacc,
                           float* __restrict__ graph,
                           const float* __restrict__ lg,
                           const float* __restrict__ lb)
{
  int row  = blockIdx.x;   // 64 graphs
  int lane = threadIdx.x;  // 64 = one wave
  float2 gv = *(const float2*)&lg[lane * 2];
  float2 bv = *(const float2*)&lb[lane * 2];
  float2 a = *(const float2*)&gacc[row * D + lane * 2];
  float2 p = *(const float2*)&graph[row * D + lane * 2];
  float x0 = a.x + p.x, x1 = a.y + p.y;
#pragma unroll
  for (int pass = 0; pass < 2; ++pass) {
    float s = x0 + x1, q = x0 * x0 + x1 * x1;
#pragma unroll
    for (int m = 1; m < 64; m <<= 1) { s += __shfl_xor(s, m); q += __shfl_xor(q, m); }
    float mean = s * (1.f / 128.f);
    float var  = q * (1.f / 128.f) - mean * mean;
    float rs   = rsqrtf(fmaxf(var, 0.f) + 1e-5f);
    x0 = (x0 - mean) * rs * gv.x + bv.x;
    x1 = (x1 - mean) * rs * gv.y + bv.y;
  }
  float2 o; o.x = x0; o.y = x1;
  *(float2*)&graph[row * D + lane * 2] = o;
}

extern "C" void kernel_launch(void* const* d_in, const int* in_sizes, int n_in,
                              void* d_out, int out_size, void* d_ws, size_t ws_size,
                              hipStream_t stream)
{
  const float* x       = (const float*)d_in[0];
  const int*   edge    = (const int*)d_in[1];
  const int*   batch   = (const int*)d_in[2];
  const float* fc_w    = (const float*)d_in[3];
  const float* fc_b    = (const float*)d_in[4];
  const float* w_self  = (const float*)d_in[5];
  const float* w_neigh = (const float*)d_in[6];
  const float* conv_b  = (const float*)d_in[7];
  const float* ln_g    = (const float*)d_in[8];
  const float* ln_b    = (const float*)d_in[9];

  const int N = in_sizes[0] / D;
  const int E = in_sizes[1] / 2;
  const int* src = edge;
  const int* dst = edge + E;

  float* node  = (float*)d_out;                 // [N*D]
  float* graph = (float*)d_out + (long)N * D;   // [G*D]

  float* deg  = (float*)d_ws;                   // N (becomes inv-deg)
  float* agg  = deg + N;                        // N*D
  float* h    = agg + (long)N * D;              // N*D
  float* gacc = h + (long)N * D;                // G*D

  hipMemsetAsync(deg, 0, (size_t)N * sizeof(float), stream);
  hipMemsetAsync(graph, 0, (size_t)NG * D * sizeof(float), stream);

  k_deg<<<2048, 256, 0, stream>>>(dst, deg, E);
  k_invdeg<<<(N + 255) / 256, 256, 0, stream>>>(deg, N);

  const int gblocks = (N + TILE_R - 1) / TILE_R;
  k_gemm<false><<<gblocks, 256, 0, stream>>>(x, nullptr, nullptr, fc_w, nullptr,
                                             fc_b, node, N);

  for (int l = 0; l < NL; ++l) {
    hipMemsetAsync(agg, 0, (size_t)N * D * sizeof(float), stream);
    hipMemsetAsync(gacc, 0, (size_t)NG * D * sizeof(float), stream);
    k_scatter<<<2048, 256, 0, stream>>>(node, src, dst, agg, (long)E * 32);
    k_gemm<true><<<gblocks, 256, 0, stream>>>(node, agg, deg,
                                              w_self + (long)l * D * D,
                                              w_neigh + (long)l * D * D,
                                              conv_b + l * D, h, N);
    k_gsum<<<(N + 511) / 512, 128, 0, stream>>>(h, batch, gacc, N);
    k_ln_graph<<<NG, 64, 0, stream>>>(gacc, graph, ln_g + l * D, ln_b + l * D);
    k_ln_node<<<1024, 256, 0, stream>>>(h, node, ln_g + l * D, ln_b + l * D, N);
  }
}

// Round 2
// 3317.178 us; speedup vs baseline: 3.2602x; 3.2602x over previous
//
#include <hip/hip_runtime.h>

#define D 128
#define NG 64
#define NL 3

constexpr int TILE_R = 32;
constexpr int LDSTR  = 132;   // padded row stride (floats), 16B-aligned

__device__ __forceinline__ float f4c(const float4& v, int i) {
  return i == 0 ? v.x : (i == 1 ? v.y : (i == 2 ? v.z : v.w));
}

// ================= CSR build =================
__global__ void k_count(const int* __restrict__ dst, int* __restrict__ cnt, int E) {
  int i = blockIdx.x * blockDim.x + threadIdx.x;
  int stride = gridDim.x * blockDim.x;
  for (; i < E; i += stride) atomicAdd(&cnt[dst[i]], 1);
}

__global__ void k_invdeg(const int* __restrict__ cnt, float* __restrict__ invdeg, int n) {
  int i = blockIdx.x * blockDim.x + threadIdx.x;
  if (i < n) invdeg[i] = 1.0f / (float)max(cnt[i], 1);
}

// per-1024-chunk sums (256 threads, 4 elems each)
__global__ void k_blocksum(const int* __restrict__ cnt, int* __restrict__ bsum, int n) {
  int b = blockIdx.x, t = threadIdx.x;
  int base = b * 1024 + t * 4;
  int s = 0;
#pragma unroll
  for (int j = 0; j < 4; ++j) if (base + j < n) s += cnt[base + j];
  int lane = t & 63, w = t >> 6;
#pragma unroll
  for (int m = 1; m < 64; m <<= 1) s += __shfl_xor(s, m);
  __shared__ int ws[4];
  if (lane == 0) ws[w] = s;
  __syncthreads();
  if (t == 0) bsum[b] = ws[0] + ws[1] + ws[2] + ws[3];
}

// single block: exclusive scan of up to 1024 chunk sums
__global__ void k_scan_bsum(int* __restrict__ bsum, int nb) {
  __shared__ int s[1024];
  int t = threadIdx.x;
  int v = t < nb ? bsum[t] : 0;
  s[t] = v;
  __syncthreads();
  for (int off = 1; off < 1024; off <<= 1) {
    int x = (t >= off) ? s[t - off] : 0;
    __syncthreads();
    s[t] += x;
    __syncthreads();
  }
  if (t < nb) bsum[t] = s[t] - v;   // exclusive
}

// rowptr (exclusive prefix of cnt) + cursor copy
__global__ void k_rowptr(const int* __restrict__ cnt, const int* __restrict__ bsum,
                         int* __restrict__ rowptr, int* __restrict__ cursor, int n) {
  int b = blockIdx.x, t = threadIdx.x;
  int base = b * 1024 + t * 4;
  int v0 = 0, v1 = 0, v2 = 0, v3 = 0;
  if (base + 0 < n) v0 = cnt[base + 0];
  if (base + 1 < n) v1 = cnt[base + 1];
  if (base + 2 < n) v2 = cnt[base + 2];
  if (base + 3 < n) v3 = cnt[base + 3];
  int ts = v0 + v1 + v2 + v3;
  int lane = t & 63, w = t >> 6;
  int incl = ts;
#pragma unroll
  for (int m = 1; m < 64; m <<= 1) {
    int o = __shfl_up(incl, m);
    if (lane >= m) incl += o;
  }
  __shared__ int wsum[4];
  if (lane == 63) wsum[w] = incl;
  __syncthreads();
  int woff = 0;
  for (int i = 0; i < w; ++i) woff += wsum[i];
  int run = incl - ts + woff + bsum[b];
  if (base + 0 < n) { rowptr[base + 0] = run; cursor[base + 0] = run; run += v0; }
  if (base + 1 < n) { rowptr[base + 1] = run; cursor[base + 1] = run; run += v1; }
  if (base + 2 < n) { rowptr[base + 2] = run; cursor[base + 2] = run; run += v2; }
  if (base + 3 < n) { rowptr[base + 3] = run; cursor[base + 3] = run; run += v3; }
}

// bucket-fill: csr_src[slot] = src, slots grouped by dst
// afterwards cursor[i] == row end of node i
__global__ void k_fill(const int* __restrict__ src, const int* __restrict__ dst,
                       int* __restrict__ cursor, int* __restrict__ csr_src, int E) {
  int i = blockIdx.x * blockDim.x + threadIdx.x;
  int stride = gridDim.x * blockDim.x;
  for (; i < E; i += stride) {
    int t = dst[i];
    int pos = atomicAdd(&cursor[t], 1);
    csr_src[pos] = src[i];
  }
}

// ================= aggregation: agg[i] = mean_{e: dst=i} node[src[e]] =================
__global__ void k_aggr(const float* __restrict__ node,
                       const int* __restrict__ rowptr, const int* __restrict__ rowend,
                       const float* __restrict__ invdeg,
                       const int* __restrict__ csr_src,
                       float* __restrict__ agg, int n) {
  int lane = threadIdx.x & 63;
  int w = (blockIdx.x * blockDim.x + threadIdx.x) >> 6;   // one wave per node
  if (w >= n) return;
  int s0 = rowptr[w], s1 = rowend[w];
  float2 acc = make_float2(0.f, 0.f);
  for (int k = s0; k < s1; ++k) {
    int s = csr_src[k];
    float2 v = *(const float2*)&node[(long)s * D + lane * 2];
    acc.x += v.x; acc.y += v.y;
  }
  float sc = invdeg[w];
  acc.x *= sc; acc.y *= sc;
  *(float2*)&agg[(long)w * D + lane * 2] = acc;
}

// ================= GEMM: H = A@Ws (+ B@Wn) + bias =================
template <bool TWO>
__global__ __launch_bounds__(256, 2) void k_gemm(
    const float* __restrict__ A, const float* __restrict__ B,
    const float* __restrict__ Ws, const float* __restrict__ Wn,
    const float* __restrict__ bias, float* __restrict__ Hout, int n)
{
  __shared__ float a_lds[TILE_R][LDSTR];
  __shared__ float b_lds[TILE_R][LDSTR];
  __shared__ float ws_lds[32][D];
  __shared__ float wn_lds[32][D];

  const int tid  = threadIdx.x;
  const int tcol = tid & 31;
  const int trow = tid >> 5;
  const long base = (long)blockIdx.x * TILE_R;

#pragma unroll
  for (int i = 0; i < 4; ++i) {
    int idx = tid + i * 256;
    int r   = idx >> 5;
    int c4  = (idx & 31) << 2;
    long rr = base + r;
    long rc = rr < n ? rr : (n - 1);
    *(float4*)&a_lds[r][c4] = *(const float4*)&A[rc * D + c4];
    if (TWO)
      *(float4*)&b_lds[r][c4] = *(const float4*)&B[rc * D + c4];
  }

  float acc[4][4] = {};

  for (int k0 = 0; k0 < D; k0 += 32) {
    __syncthreads();
#pragma unroll
    for (int i = 0; i < 4; ++i) {
      int idx = tid + i * 256;
      int r   = idx >> 5;
      int c4  = (idx & 31) << 2;
      *(float4*)&ws_lds[r][c4] = *(const float4*)&Ws[(long)(k0 + r) * D + c4];
      if (TWO)
        *(float4*)&wn_lds[r][c4] = *(const float4*)&Wn[(long)(k0 + r) * D + c4];
    }
    __syncthreads();

#pragma unroll
    for (int kc = 0; kc < 8; ++kc) {
      float4 a0 = *(const float4*)&a_lds[trow * 4 + 0][k0 + kc * 4];
      float4 a1 = *(const float4*)&a_lds[trow * 4 + 1][k0 + kc * 4];
      float4 a2 = *(const float4*)&a_lds[trow * 4 + 2][k0 + kc * 4];
      float4 a3 = *(const float4*)&a_lds[trow * 4 + 3][k0 + kc * 4];
      float4 b0, b1, b2, b3;
      if (TWO) {
        b0 = *(const float4*)&b_lds[trow * 4 + 0][k0 + kc * 4];
        b1 = *(const float4*)&b_lds[trow * 4 + 1][k0 + kc * 4];
        b2 = *(const float4*)&b_lds[trow * 4 + 2][k0 + kc * 4];
        b3 = *(const float4*)&b_lds[trow * 4 + 3][k0 + kc * 4];
      }
#pragma unroll
      for (int kk = 0; kk < 4; ++kk) {
        float4 ws = *(const float4*)&ws_lds[kc * 4 + kk][tcol * 4];
        float av0 = f4c(a0, kk), av1 = f4c(a1, kk), av2 = f4c(a2, kk), av3 = f4c(a3, kk);
        acc[0][0] += av0 * ws.x; acc[0][1] += av0 * ws.y; acc[0][2] += av0 * ws.z; acc[0][3] += av0 * ws.w;
        acc[1][0] += av1 * ws.x; acc[1][1] += av1 * ws.y; acc[1][2] += av1 * ws.z; acc[1][3] += av1 * ws.w;
        acc[2][0] += av2 * ws.x; acc[2][1] += av2 * ws.y; acc[2][2] += av2 * ws.z; acc[2][3] += av2 * ws.w;
        acc[3][0] += av3 * ws.x; acc[3][1] += av3 * ws.y; acc[3][2] += av3 * ws.z; acc[3][3] += av3 * ws.w;
        if (TWO) {
          float4 wn = *(const float4*)&wn_lds[kc * 4 + kk][tcol * 4];
          float bv0 = f4c(b0, kk), bv1 = f4c(b1, kk), bv2 = f4c(b2, kk), bv3 = f4c(b3, kk);
          acc[0][0] += bv0 * wn.x; acc[0][1] += bv0 * wn.y; acc[0][2] += bv0 * wn.z; acc[0][3] += bv0 * wn.w;
          acc[1][0] += bv1 * wn.x; acc[1][1] += bv1 * wn.y; acc[1][2] += bv1 * wn.z; acc[1][3] += bv1 * wn.w;
          acc[2][0] += bv2 * wn.x; acc[2][1] += bv2 * wn.y; acc[2][2] += bv2 * wn.z; acc[2][3] += bv2 * wn.w;
          acc[3][0] += bv3 * wn.x; acc[3][1] += bv3 * wn.y; acc[3][2] += bv3 * wn.z; acc[3][3] += bv3 * wn.w;
        }
      }
    }
  }

  float4 bs = *(const float4*)&bias[tcol * 4];
#pragma unroll
  for (int r = 0; r < 4; ++r) {
    long row = base + trow * 4 + r;
    if (row < n) {
      float4 o;
      o.x = acc[r][0] + bs.x; o.y = acc[r][1] + bs.y;
      o.z = acc[r][2] + bs.z; o.w = acc[r][3] + bs.w;
      *(float4*)&Hout[row * D + tcol * 4] = o;
    }
  }
}

// ================= graph segment sum (batch sorted) =================
__global__ void k_gsum(const float* __restrict__ h,
                       const int* __restrict__ batch,
                       float* __restrict__ gacc, int n)
{
  const int d = threadIdx.x;                // 128 threads, one per dim
  int r0 = blockIdx.x * 256;
  int r1 = min(n, r0 + 256);
  if (r0 >= n) return;
  float acc = 0.f;
  int cur = batch[r0];
  for (int r = r0; r < r1; ++r) {
    int b = batch[r];
    if (b != cur) { atomicAdd(&gacc[cur * D + d], acc); acc = 0.f; cur = b; }
    acc += h[(long)r * D + d];
  }
  atomicAdd(&gacc[cur * D + d], acc);
}

// ================= node LN: node = relu(LN(h + node)) =================
__global__ void k_ln_node(const float* __restrict__ h,
                          float* __restrict__ node,
                          const float* __restrict__ lg,
                          const float* __restrict__ lb, int n)
{
  int lane = threadIdx.x & 63;
  long wid = (((long)blockIdx.x * blockDim.x + threadIdx.x) >> 6);
  long nw  = (((long)gridDim.x * blockDim.x) >> 6);
  float2 gv = *(const float2*)&lg[lane * 2];
  float2 bv = *(const float2*)&lb[lane * 2];
  for (long r = wid; r < n; r += nw) {
    float2 hv = *(const float2*)&h[r * D + lane * 2];
    float2 nv = *(const float2*)&node[r * D + lane * 2];
    float x0 = hv.x + nv.x, x1 = hv.y + nv.y;
    float s = x0 + x1, q = x0 * x0 + x1 * x1;
#pragma unroll
    for (int m = 1; m < 64; m <<= 1) { s += __shfl_xor(s, m); q += __shfl_xor(q, m); }
    float mean = s * (1.f / 128.f);
    float var  = q * (1.f / 128.f) - mean * mean;
    float rs   = rsqrtf(fmaxf(var, 0.f) + 1e-5f);
    float y0 = (x0 - mean) * rs * gv.x + bv.x;
    float y1 = (x1 - mean) * rs * gv.y + bv.y;
    float2 o; o.x = fmaxf(y0, 0.f); o.y = fmaxf(y1, 0.f);
    *(float2*)&node[r * D + lane * 2] = o;
  }
}

// ================= graph LN: graph = LN(LN(gacc + graph)) =================
__global__ void k_ln_graph(const float* __restrict__ gacc,
                           float* __restrict__ graph,
                           const float* __restrict__ lg,
                           const float* __restrict__ lb)
{
  int row  = blockIdx.x;
  int lane = threadIdx.x;
  float2 gv = *(const float2*)&lg[lane * 2];
  float2 bv = *(const float2*)&lb[lane * 2];
  float2 a = *(const float2*)&gacc[row * D + lane * 2];
  float2 p = *(const float2*)&graph[row * D + lane * 2];
  float x0 = a.x + p.x, x1 = a.y + p.y;
#pragma unroll
  for (int pass = 0; pass < 2; ++pass) {
    float s = x0 + x1, q = x0 * x0 + x1 * x1;
#pragma unroll
    for (int m = 1; m < 64; m <<= 1) { s += __shfl_xor(s, m); q += __shfl_xor(q, m); }
    float mean = s * (1.f / 128.f);
    float var  = q * (1.f / 128.f) - mean * mean;
    float rs   = rsqrtf(fmaxf(var, 0.f) + 1e-5f);
    x0 = (x0 - mean) * rs * gv.x + bv.x;
    x1 = (x1 - mean) * rs * gv.y + bv.y;
  }
  float2 o; o.x = x0; o.y = x1;
  *(float2*)&graph[row * D + lane * 2] = o;
}

extern "C" void kernel_launch(void* const* d_in, const int* in_sizes, int n_in,
                              void* d_out, int out_size, void* d_ws, size_t ws_size,
                              hipStream_t stream)
{
  const float* x       = (const float*)d_in[0];
  const int*   edge    = (const int*)d_in[1];
  const int*   batch   = (const int*)d_in[2];
  const float* fc_w    = (const float*)d_in[3];
  const float* fc_b    = (const float*)d_in[4];
  const float* w_self  = (const float*)d_in[5];
  const float* w_neigh = (const float*)d_in[6];
  const float* conv_b  = (const float*)d_in[7];
  const float* ln_g    = (const float*)d_in[8];
  const float* ln_b    = (const float*)d_in[9];

  const int N = in_sizes[0] / D;
  const int E = in_sizes[1] / 2;
  const int* src = edge;
  const int* dst = edge + E;

  float* node  = (float*)d_out;                 // [N*D]
  float* graph = (float*)d_out + (long)N * D;   // [G*D]

  // workspace layout
  int*   cnt     = (int*)d_ws;                  // N
  int*   rowptr  = cnt + N;                     // N
  int*   cursor  = rowptr + N;                  // N (ends as row-end)
  int*   bsum    = cursor + N;                  // 1024
  int*   csr_src = bsum + 1024;                 // E
  float* invdeg  = (float*)(csr_src + E);       // N
  float* agg     = invdeg + N;                  // N*D  (also GEMM output h, in-place)
  float* gacc    = agg + (long)N * D;           // G*D
  float* h       = agg;                         // alias

  const int nb = (N + 1023) / 1024;

  hipMemsetAsync(cnt, 0, (size_t)N * sizeof(int), stream);
  hipMemsetAsync(graph, 0, (size_t)NG * D * sizeof(float), stream);

  // ---- CSR build (once) ----
  k_count<<<2048, 256, 0, stream>>>(dst, cnt, E);
  k_invdeg<<<(N + 255) / 256, 256, 0, stream>>>(cnt, invdeg, N);
  k_blocksum<<<nb, 256, 0, stream>>>(cnt, bsum, N);
  k_scan_bsum<<<1, 1024, 0, stream>>>(bsum, nb);
  k_rowptr<<<nb, 256, 0, stream>>>(cnt, bsum, rowptr, cursor, N);
  k_fill<<<2048, 256, 0, stream>>>(src, dst, cursor, csr_src, E);

  // ---- input projection ----
  const int gblocks = (N + TILE_R - 1) / TILE_R;
  k_gemm<false><<<gblocks, 256, 0, stream>>>(x, nullptr, fc_w, nullptr,
                                             fc_b, node, N);

  for (int l = 0; l < NL; ++l) {
    hipMemsetAsync(gacc, 0, (size_t)NG * D * sizeof(float), stream);
    k_aggr<<<(N + 3) / 4, 256, 0, stream>>>(node, rowptr, cursor, invdeg,
                                            csr_src, agg, N);
    k_gemm<true><<<gblocks, 256, 0, stream>>>(node, agg,
                                              w_self + (long)l * D * D,
                                              w_neigh + (long)l * D * D,
                                              conv_b + l * D, h, N);
    k_gsum<<<(N + 255) / 256, 128, 0, stream>>>(h, batch, gacc, N);
    k_ln_graph<<<NG, 64, 0, stream>>>(gacc, graph, ln_g + l * D, ln_b + l * D);
    k_ln_node<<<1024, 256, 0, stream>>>(h, node, ln_g + l * D, ln_b + l * D, N);
  }
}

// Round 3
// 3275.855 us; speedup vs baseline: 3.3013x; 1.0126x over previous
//
#include <hip/hip_runtime.h>

#define D 128
#define NG 64
#define NL 3

constexpr int TILE_R = 32;
constexpr int LDSTR  = 132;   // padded row stride (floats), 528B rows, 16B-aligned

__device__ __forceinline__ float f4c(const float4& v, int i) {
  return i == 0 ? v.x : (i == 1 ? v.y : (i == 2 ? v.z : v.w));
}

// ================= CSR build =================
__global__ void k_count(const int* __restrict__ dst, int* __restrict__ cnt, int E) {
  int i = blockIdx.x * blockDim.x + threadIdx.x;
  int stride = gridDim.x * blockDim.x;
  for (; i < E; i += stride) atomicAdd(&cnt[dst[i]], 1);
}

__global__ void k_invdeg(const int* __restrict__ cnt, float* __restrict__ invdeg, int n) {
  int i = blockIdx.x * blockDim.x + threadIdx.x;
  if (i < n) invdeg[i] = 1.0f / (float)max(cnt[i], 1);
}

__global__ void k_blocksum(const int* __restrict__ cnt, int* __restrict__ bsum, int n) {
  int b = blockIdx.x, t = threadIdx.x;
  int base = b * 1024 + t * 4;
  int s = 0;
#pragma unroll
  for (int j = 0; j < 4; ++j) if (base + j < n) s += cnt[base + j];
  int lane = t & 63, w = t >> 6;
#pragma unroll
  for (int m = 1; m < 64; m <<= 1) s += __shfl_xor(s, m);
  __shared__ int ws[4];
  if (lane == 0) ws[w] = s;
  __syncthreads();
  if (t == 0) bsum[b] = ws[0] + ws[1] + ws[2] + ws[3];
}

__global__ void k_scan_bsum(int* __restrict__ bsum, int nb) {
  __shared__ int s[1024];
  int t = threadIdx.x;
  int v = t < nb ? bsum[t] : 0;
  s[t] = v;
  __syncthreads();
  for (int off = 1; off < 1024; off <<= 1) {
    int x = (t >= off) ? s[t - off] : 0;
    __syncthreads();
    s[t] += x;
    __syncthreads();
  }
  if (t < nb) bsum[t] = s[t] - v;   // exclusive
}

__global__ void k_rowptr(const int* __restrict__ cnt, const int* __restrict__ bsum,
                         int* __restrict__ rowptr, int* __restrict__ cursor, int n) {
  int b = blockIdx.x, t = threadIdx.x;
  int base = b * 1024 + t * 4;
  int v0 = 0, v1 = 0, v2 = 0, v3 = 0;
  if (base + 0 < n) v0 = cnt[base + 0];
  if (base + 1 < n) v1 = cnt[base + 1];
  if (base + 2 < n) v2 = cnt[base + 2];
  if (base + 3 < n) v3 = cnt[base + 3];
  int ts = v0 + v1 + v2 + v3;
  int lane = t & 63, w = t >> 6;
  int incl = ts;
#pragma unroll
  for (int m = 1; m < 64; m <<= 1) {
    int o = __shfl_up(incl, m);
    if (lane >= m) incl += o;
  }
  __shared__ int wsum[4];
  if (lane == 63) wsum[w] = incl;
  __syncthreads();
  int woff = 0;
  for (int i = 0; i < w; ++i) woff += wsum[i];
  int run = incl - ts + woff + bsum[b];
  if (base + 0 < n) { rowptr[base + 0] = run; cursor[base + 0] = run; run += v0; }
  if (base + 1 < n) { rowptr[base + 1] = run; cursor[base + 1] = run; run += v1; }
  if (base + 2 < n) { rowptr[base + 2] = run; cursor[base + 2] = run; run += v2; }
  if (base + 3 < n) { rowptr[base + 3] = run; cursor[base + 3] = run; run += v3; }
}

__global__ void k_fill(const int* __restrict__ src, const int* __restrict__ dst,
                       int* __restrict__ cursor, int* __restrict__ csr_src, int E) {
  int i = blockIdx.x * blockDim.x + threadIdx.x;
  int stride = gridDim.x * blockDim.x;
  for (; i < E; i += stride) {
    int t = dst[i];
    int pos = atomicAdd(&cursor[t], 1);
    csr_src[pos] = src[i];
  }
}

// ================= aggregation: agg[i] = mean_{e: dst=i} node[src[e]] =================
__global__ void k_aggr(const float* __restrict__ node,
                       const int* __restrict__ rowptr, const int* __restrict__ rowend,
                       const float* __restrict__ invdeg,
                       const int* __restrict__ csr_src,
                       float* __restrict__ agg, int n) {
  int lane = threadIdx.x & 63;
  int w = (blockIdx.x * blockDim.x + threadIdx.x) >> 6;   // one wave per node
  if (w >= n) return;
  int s0 = rowptr[w], s1 = rowend[w];
  float2 acc = make_float2(0.f, 0.f);
  for (int k = s0; k < s1; ++k) {
    int s = csr_src[k];
    float2 v = *(const float2*)&node[(long)s * D + lane * 2];
    acc.x += v.x; acc.y += v.y;
  }
  float sc = invdeg[w];
  acc.x *= sc; acc.y *= sc;
  *(float2*)&agg[(long)w * D + lane * 2] = acc;
}

// ================= GEMM: H = A@Ws (+ B@Wn) + bias; optional fused res+LN+relu ===========
// LN epilogue: NodeOut = relu(LN(H + A_row)) — A_row comes from the staged a_lds tile.
template <bool TWO, bool LN>
__global__ __launch_bounds__(256, 2) void k_gemm(
    const float* __restrict__ A, const float* __restrict__ B,
    const float* __restrict__ Ws, const float* __restrict__ Wn,
    const float* __restrict__ bias,
    const float* __restrict__ lg, const float* __restrict__ lb,
    float* __restrict__ Hout, float* __restrict__ NodeOut, int n)
{
  __shared__ float a_lds[TILE_R][LDSTR];
  __shared__ float b_lds[TILE_R][LDSTR];
  __shared__ float ws_lds[32][D];
  __shared__ float wn_lds[32][D];

  const int tid  = threadIdx.x;
  const int tcol = tid & 31;
  const int trow = tid >> 5;
  const long base = (long)blockIdx.x * TILE_R;

#pragma unroll
  for (int i = 0; i < 4; ++i) {
    int idx = tid + i * 256;
    int r   = idx >> 5;
    int c4  = (idx & 31) << 2;
    long rr = base + r;
    long rc = rr < n ? rr : (n - 1);
    *(float4*)&a_lds[r][c4] = *(const float4*)&A[rc * D + c4];
    if (TWO)
      *(float4*)&b_lds[r][c4] = *(const float4*)&B[rc * D + c4];
  }

  float acc[4][4] = {};

  for (int k0 = 0; k0 < D; k0 += 32) {
    __syncthreads();
#pragma unroll
    for (int i = 0; i < 4; ++i) {
      int idx = tid + i * 256;
      int r   = idx >> 5;
      int c4  = (idx & 31) << 2;
      *(float4*)&ws_lds[r][c4] = *(const float4*)&Ws[(long)(k0 + r) * D + c4];
      if (TWO)
        *(float4*)&wn_lds[r][c4] = *(const float4*)&Wn[(long)(k0 + r) * D + c4];
    }
    __syncthreads();

#pragma unroll
    for (int kc = 0; kc < 8; ++kc) {
      float4 a0 = *(const float4*)&a_lds[trow * 4 + 0][k0 + kc * 4];
      float4 a1 = *(const float4*)&a_lds[trow * 4 + 1][k0 + kc * 4];
      float4 a2 = *(const float4*)&a_lds[trow * 4 + 2][k0 + kc * 4];
      float4 a3 = *(const float4*)&a_lds[trow * 4 + 3][k0 + kc * 4];
      float4 b0, b1, b2, b3;
      if (TWO) {
        b0 = *(const float4*)&b_lds[trow * 4 + 0][k0 + kc * 4];
        b1 = *(const float4*)&b_lds[trow * 4 + 1][k0 + kc * 4];
        b2 = *(const float4*)&b_lds[trow * 4 + 2][k0 + kc * 4];
        b3 = *(const float4*)&b_lds[trow * 4 + 3][k0 + kc * 4];
      }
#pragma unroll
      for (int kk = 0; kk < 4; ++kk) {
        float4 ws = *(const float4*)&ws_lds[kc * 4 + kk][tcol * 4];
        float av0 = f4c(a0, kk), av1 = f4c(a1, kk), av2 = f4c(a2, kk), av3 = f4c(a3, kk);
        acc[0][0] += av0 * ws.x; acc[0][1] += av0 * ws.y; acc[0][2] += av0 * ws.z; acc[0][3] += av0 * ws.w;
        acc[1][0] += av1 * ws.x; acc[1][1] += av1 * ws.y; acc[1][2] += av1 * ws.z; acc[1][3] += av1 * ws.w;
        acc[2][0] += av2 * ws.x; acc[2][1] += av2 * ws.y; acc[2][2] += av2 * ws.z; acc[2][3] += av2 * ws.w;
        acc[3][0] += av3 * ws.x; acc[3][1] += av3 * ws.y; acc[3][2] += av3 * ws.z; acc[3][3] += av3 * ws.w;
        if (TWO) {
          float4 wn = *(const float4*)&wn_lds[kc * 4 + kk][tcol * 4];
          float bv0 = f4c(b0, kk), bv1 = f4c(b1, kk), bv2 = f4c(b2, kk), bv3 = f4c(b3, kk);
          acc[0][0] += bv0 * wn.x; acc[0][1] += bv0 * wn.y; acc[0][2] += bv0 * wn.z; acc[0][3] += bv0 * wn.w;
          acc[1][0] += bv1 * wn.x; acc[1][1] += bv1 * wn.y; acc[1][2] += bv1 * wn.z; acc[1][3] += bv1 * wn.w;
          acc[2][0] += bv2 * wn.x; acc[2][1] += bv2 * wn.y; acc[2][2] += bv2 * wn.z; acc[2][3] += bv2 * wn.w;
          acc[3][0] += bv3 * wn.x; acc[3][1] += bv3 * wn.y; acc[3][2] += bv3 * wn.z; acc[3][3] += bv3 * wn.w;
        }
      }
    }
  }

  float4 bs = *(const float4*)&bias[tcol * 4];
  float4 gv, bv2;
  if (LN) {
    gv  = *(const float4*)&lg[tcol * 4];
    bv2 = *(const float4*)&lb[tcol * 4];
  }
#pragma unroll
  for (int r = 0; r < 4; ++r) {
    long row = base + trow * 4 + r;
    float4 o;
    o.x = acc[r][0] + bs.x; o.y = acc[r][1] + bs.y;
    o.z = acc[r][2] + bs.z; o.w = acc[r][3] + bs.w;
    if (row < n) *(float4*)&Hout[row * D + tcol * 4] = o;
    if (LN) {
      // residual: the staged A tile IS the node tile
      float4 av = *(const float4*)&a_lds[trow * 4 + r][tcol * 4];
      o.x += av.x; o.y += av.y; o.z += av.z; o.w += av.w;
      float s = o.x + o.y + o.z + o.w;
      float q = o.x * o.x + o.y * o.y + o.z * o.z + o.w * o.w;
#pragma unroll
      for (int m = 1; m < 32; m <<= 1) { s += __shfl_xor(s, m); q += __shfl_xor(q, m); }
      float mean = s * (1.f / 128.f);
      float var  = q * (1.f / 128.f) - mean * mean;
      float rs   = rsqrtf(fmaxf(var, 0.f) + 1e-5f);
      float4 y;
      y.x = fmaxf((o.x - mean) * rs * gv.x + bv2.x, 0.f);
      y.y = fmaxf((o.y - mean) * rs * gv.y + bv2.y, 0.f);
      y.z = fmaxf((o.z - mean) * rs * gv.z + bv2.z, 0.f);
      y.w = fmaxf((o.w - mean) * rs * gv.w + bv2.w, 0.f);
      if (row < n) *(float4*)&NodeOut[row * D + tcol * 4] = y;
    }
  }
}

// ================= graph segment sum (batch sorted) =================
__global__ void k_gsum(const float* __restrict__ h,
                       const int* __restrict__ batch,
                       float* __restrict__ gacc, int n)
{
  const int d = threadIdx.x;                // 128 threads, one per dim
  int r0 = blockIdx.x * 256;
  int r1 = min(n, r0 + 256);
  if (r0 >= n) return;
  float acc = 0.f;
  int cur = batch[r0];
  for (int r = r0; r < r1; ++r) {
    int b = batch[r];
    if (b != cur) { atomicAdd(&gacc[cur * D + d], acc); acc = 0.f; cur = b; }
    acc += h[(long)r * D + d];
  }
  atomicAdd(&gacc[cur * D + d], acc);
}

// ================= graph LN: graph = LN(LN(gacc + graph)) =================
__global__ void k_ln_graph(const float* __restrict__ gacc,
                           float* __restrict__ graph,
                           const float* __restrict__ lg,
                           const float* __restrict__ lb)
{
  int row  = blockIdx.x;
  int lane = threadIdx.x;
  float2 gv = *(const float2*)&lg[lane * 2];
  float2 bv = *(const float2*)&lb[lane * 2];
  float2 a = *(const float2*)&gacc[row * D + lane * 2];
  float2 p = *(const float2*)&graph[row * D + lane * 2];
  float x0 = a.x + p.x, x1 = a.y + p.y;
#pragma unroll
  for (int pass = 0; pass < 2; ++pass) {
    float s = x0 + x1, q = x0 * x0 + x1 * x1;
#pragma unroll
    for (int m = 1; m < 64; m <<= 1) { s += __shfl_xor(s, m); q += __shfl_xor(q, m); }
    float mean = s * (1.f / 128.f);
    float var  = q * (1.f / 128.f) - mean * mean;
    float rs   = rsqrtf(fmaxf(var, 0.f) + 1e-5f);
    x0 = (x0 - mean) * rs * gv.x + bv.x;
    x1 = (x1 - mean) * rs * gv.y + bv.y;
  }
  float2 o; o.x = x0; o.y = x1;
  *(float2*)&graph[row * D + lane * 2] = o;
}

extern "C" void kernel_launch(void* const* d_in, const int* in_sizes, int n_in,
                              void* d_out, int out_size, void* d_ws, size_t ws_size,
                              hipStream_t stream)
{
  const float* x       = (const float*)d_in[0];
  const int*   edge    = (const int*)d_in[1];
  const int*   batch   = (const int*)d_in[2];
  const float* fc_w    = (const float*)d_in[3];
  const float* fc_b    = (const float*)d_in[4];
  const float* w_self  = (const float*)d_in[5];
  const float* w_neigh = (const float*)d_in[6];
  const float* conv_b  = (const float*)d_in[7];
  const float* ln_g    = (const float*)d_in[8];
  const float* ln_b    = (const float*)d_in[9];

  const int N = in_sizes[0] / D;
  const int E = in_sizes[1] / 2;
  const int* src = edge;
  const int* dst = edge + E;

  // ---- workspace layout (everything hot lives in ws; d_out is write-only) ----
  int*   cnt      = (int*)d_ws;                 // N
  int*   rowptr   = cnt + N;                    // N
  int*   cursor   = rowptr + N;                 // N (ends as row-end)
  int*   bsum     = cursor + N;                 // 1024
  int*   csr_src  = bsum + 1024;                // E
  float* invdeg   = (float*)(csr_src + E);      // N
  float* gacc     = invdeg + N;                 // G*D
  float* graphbuf = gacc + NG * D;              // G*D
  float* nodebuf  = graphbuf + NG * D;          // N*D
  float* agg      = nodebuf + (long)N * D;      // N*D (aliases: xbuf, h)
  float* xbuf     = agg;                        // x copy (dead after projection)
  float* h        = agg;                        // GEMM raw output (in-place over agg)

  const int nb = (N + 1023) / 1024;

  hipMemsetAsync(cnt, 0, (size_t)N * sizeof(int), stream);
  hipMemsetAsync(graphbuf, 0, (size_t)NG * D * sizeof(float), stream);

  // pull x into ws so no hot kernel streams from d_in
  hipMemcpyAsync(xbuf, x, (size_t)N * D * sizeof(float),
                 hipMemcpyDeviceToDevice, stream);

  // ---- CSR build (once) ----
  k_count<<<2048, 256, 0, stream>>>(dst, cnt, E);
  k_invdeg<<<(N + 255) / 256, 256, 0, stream>>>(cnt, invdeg, N);
  k_blocksum<<<nb, 256, 0, stream>>>(cnt, bsum, N);
  k_scan_bsum<<<1, 1024, 0, stream>>>(bsum, nb);
  k_rowptr<<<nb, 256, 0, stream>>>(cnt, bsum, rowptr, cursor, N);
  k_fill<<<2048, 256, 0, stream>>>(src, dst, cursor, csr_src, E);

  // ---- input projection: nodebuf = xbuf @ fc_w + fc_b ----
  const int gblocks = (N + TILE_R - 1) / TILE_R;
  k_gemm<false, false><<<gblocks, 256, 0, stream>>>(
      xbuf, nullptr, fc_w, nullptr, fc_b, nullptr, nullptr,
      nodebuf, nullptr, N);

  for (int l = 0; l < NL; ++l) {
    hipMemsetAsync(gacc, 0, (size_t)NG * D * sizeof(float), stream);
    k_aggr<<<(N + 3) / 4, 256, 0, stream>>>(nodebuf, rowptr, cursor, invdeg,
                                            csr_src, agg, N);
    // h (=agg in-place) gets raw conv output; nodebuf gets relu(LN(h+node))
    k_gemm<true, true><<<gblocks, 256, 0, stream>>>(
        nodebuf, agg,
        w_self + (long)l * D * D, w_neigh + (long)l * D * D,
        conv_b + l * D, ln_g + l * D, ln_b + l * D,
        h, nodebuf, N);
    k_gsum<<<(N + 255) / 256, 128, 0, stream>>>(h, batch, gacc, N);
    k_ln_graph<<<NG, 64, 0, stream>>>(gacc, graphbuf, ln_g + l * D, ln_b + l * D);
  }

  // ---- single write of outputs ----
  hipMemcpyAsync(d_out, nodebuf, (size_t)N * D * sizeof(float),
                 hipMemcpyDeviceToDevice, stream);
  hipMemcpyAsync((float*)d_out + (long)N * D, graphbuf,
                 (size_t)NG * D * sizeof(float),
                 hipMemcpyDeviceToDevice, stream);
}

// Round 4
// 1486.367 us; speedup vs baseline: 7.2758x; 2.2039x over previous
//
#include <hip/hip_runtime.h>

#define D 128
#define NG 64
#define NL 3

constexpr int TILE_R = 32;
constexpr int LDSTR  = 132;   // padded row stride (floats), 528B rows, 16B-aligned

__device__ __forceinline__ float f4c(const float4& v, int i) {
  return i == 0 ? v.x : (i == 1 ? v.y : (i == 2 ? v.z : v.w));
}

// ================= CSR build =================
__global__ void k_count(const int* __restrict__ dst, int* __restrict__ cnt, int E) {
  int i = blockIdx.x * blockDim.x + threadIdx.x;
  int stride = gridDim.x * blockDim.x;
  for (; i < E; i += stride) atomicAdd(&cnt[dst[i]], 1);
}

__global__ void k_invdeg(const int* __restrict__ cnt, float* __restrict__ invdeg, int n) {
  int i = blockIdx.x * blockDim.x + threadIdx.x;
  if (i < n) invdeg[i] = 1.0f / (float)max(cnt[i], 1);
}

__global__ void k_blocksum(const int* __restrict__ cnt, int* __restrict__ bsum, int n) {
  int b = blockIdx.x, t = threadIdx.x;
  int base = b * 1024 + t * 4;
  int s = 0;
#pragma unroll
  for (int j = 0; j < 4; ++j) if (base + j < n) s += cnt[base + j];
  int lane = t & 63, w = t >> 6;
#pragma unroll
  for (int m = 1; m < 64; m <<= 1) s += __shfl_xor(s, m);
  __shared__ int ws[4];
  if (lane == 0) ws[w] = s;
  __syncthreads();
  if (t == 0) bsum[b] = ws[0] + ws[1] + ws[2] + ws[3];
}

__global__ void k_scan_bsum(int* __restrict__ bsum, int nb) {
  __shared__ int s[1024];
  int t = threadIdx.x;
  int v = t < nb ? bsum[t] : 0;
  s[t] = v;
  __syncthreads();
  for (int off = 1; off < 1024; off <<= 1) {
    int x = (t >= off) ? s[t - off] : 0;
    __syncthreads();
    s[t] += x;
    __syncthreads();
  }
  if (t < nb) bsum[t] = s[t] - v;   // exclusive
}

__global__ void k_rowptr(const int* __restrict__ cnt, const int* __restrict__ bsum,
                         int* __restrict__ rowptr, int* __restrict__ cursor, int n) {
  int b = blockIdx.x, t = threadIdx.x;
  int base = b * 1024 + t * 4;
  int v0 = 0, v1 = 0, v2 = 0, v3 = 0;
  if (base + 0 < n) v0 = cnt[base + 0];
  if (base + 1 < n) v1 = cnt[base + 1];
  if (base + 2 < n) v2 = cnt[base + 2];
  if (base + 3 < n) v3 = cnt[base + 3];
  int ts = v0 + v1 + v2 + v3;
  int lane = t & 63, w = t >> 6;
  int incl = ts;
#pragma unroll
  for (int m = 1; m < 64; m <<= 1) {
    int o = __shfl_up(incl, m);
    if (lane >= m) incl += o;
  }
  __shared__ int wsum[4];
  if (lane == 63) wsum[w] = incl;
  __syncthreads();
  int woff = 0;
  for (int i = 0; i < w; ++i) woff += wsum[i];
  int run = incl - ts + woff + bsum[b];
  if (base + 0 < n) { rowptr[base + 0] = run; cursor[base + 0] = run; run += v0; }
  if (base + 1 < n) { rowptr[base + 1] = run; cursor[base + 1] = run; run += v1; }
  if (base + 2 < n) { rowptr[base + 2] = run; cursor[base + 2] = run; run += v2; }
  if (base + 3 < n) { rowptr[base + 3] = run; cursor[base + 3] = run; run += v3; }
}

__global__ void k_fill(const int* __restrict__ src, const int* __restrict__ dst,
                       int* __restrict__ cursor, int* __restrict__ csr_src, int E) {
  int i = blockIdx.x * blockDim.x + threadIdx.x;
  int stride = gridDim.x * blockDim.x;
  for (; i < E; i += stride) {
    int t = dst[i];
    int pos = atomicAdd(&cursor[t], 1);
    csr_src[pos] = src[i];
  }
}

// ================= aggregation: agg[i] = mean_{e: dst=i} node[src[e]] =================
__global__ void k_aggr(const float* __restrict__ node,
                       const int* __restrict__ rowptr, const int* __restrict__ rowend,
                       const float* __restrict__ invdeg,
                       const int* __restrict__ csr_src,
                       float* __restrict__ agg, int n) {
  int lane = threadIdx.x & 63;
  int w = (blockIdx.x * blockDim.x + threadIdx.x) >> 6;   // one wave per node
  if (w >= n) return;
  int s0 = rowptr[w], s1 = rowend[w];
  float2 acc = make_float2(0.f, 0.f);
  for (int k = s0; k < s1; ++k) {
    int s = csr_src[k];
    float2 v = *(const float2*)&node[(long)s * D + lane * 2];
    acc.x += v.x; acc.y += v.y;
  }
  float sc = invdeg[w];
  acc.x *= sc; acc.y *= sc;
  *(float2*)&agg[(long)w * D + lane * 2] = acc;
}

// ================= projection: Out = X @ W + b  (whole W in LDS) =================
__global__ __launch_bounds__(256, 2) void k_proj(
    const float* __restrict__ X, const float* __restrict__ W,
    const float* __restrict__ bias, float* __restrict__ Out, int n)
{
  __shared__ float w_lds[D * D];    // 64 KB, staged once
  __shared__ float xr[4][LDSTR];    // per-wave row buffer

  const int tid  = threadIdx.x;
  const int lane = tid & 63;
  const int w    = tid >> 6;

  // stage full W: 16 float4 per thread, coalesced
#pragma unroll
  for (int i = 0; i < 16; ++i) {
    int off = i * 1024 + tid * 4;
    *(float4*)&w_lds[off] = *(const float4*)&W[off];
  }
  __syncthreads();

  const float2 bs = *(const float2*)&bias[lane * 2];
  const int nwaves = gridDim.x * 4;

  for (int row = blockIdx.x * 4 + w; row < n; row += nwaves) {
    float2 xv = *(const float2*)&X[(long)row * D + lane * 2];
    *(float2*)&xr[w][lane * 2] = xv;          // wave-private buffer, no barrier
    float acc0 = bs.x, acc1 = bs.y;
#pragma unroll
    for (int k0 = 0; k0 < D; k0 += 4) {
      float4 xb = *(const float4*)&xr[w][k0]; // broadcast (same addr all lanes)
#pragma unroll
      for (int kk = 0; kk < 4; ++kk) {
        float2 wv = *(const float2*)&w_lds[(k0 + kk) * D + lane * 2];
        float xs = f4c(xb, kk);
        acc0 += xs * wv.x;
        acc1 += xs * wv.y;
      }
    }
    float2 o; o.x = acc0; o.y = acc1;
    *(float2*)&Out[(long)row * D + lane * 2] = o;
  }
}

// ================= conv GEMM: H = A@Ws + B@Wn + bias; fused res+LN+relu ===========
__global__ __launch_bounds__(256, 2) void k_conv(
    const float* __restrict__ A, const float* __restrict__ B,
    const float* __restrict__ Ws, const float* __restrict__ Wn,
    const float* __restrict__ bias,
    const float* __restrict__ lg, const float* __restrict__ lb,
    float* __restrict__ Hout, float* __restrict__ NodeOut, int n)
{
  __shared__ float a_lds[TILE_R][LDSTR];
  __shared__ float b_lds[TILE_R][LDSTR];
  __shared__ float ws_lds[32][D];
  __shared__ float wn_lds[32][D];

  const int tid  = threadIdx.x;
  const int tcol = tid & 31;
  const int trow = tid >> 5;
  const long base = (long)blockIdx.x * TILE_R;

#pragma unroll
  for (int i = 0; i < 4; ++i) {
    int idx = tid + i * 256;
    int r   = idx >> 5;
    int c4  = (idx & 31) << 2;
    long rr = base + r;
    long rc = rr < n ? rr : (n - 1);
    *(float4*)&a_lds[r][c4] = *(const float4*)&A[rc * D + c4];
    *(float4*)&b_lds[r][c4] = *(const float4*)&B[rc * D + c4];
  }

  float acc[4][4] = {};

  for (int k0 = 0; k0 < D; k0 += 32) {
    __syncthreads();
#pragma unroll
    for (int i = 0; i < 4; ++i) {
      int idx = tid + i * 256;
      int r   = idx >> 5;
      int c4  = (idx & 31) << 2;
      *(float4*)&ws_lds[r][c4] = *(const float4*)&Ws[(long)(k0 + r) * D + c4];
      *(float4*)&wn_lds[r][c4] = *(const float4*)&Wn[(long)(k0 + r) * D + c4];
    }
    __syncthreads();

#pragma unroll
    for (int kc = 0; kc < 8; ++kc) {
      float4 a0 = *(const float4*)&a_lds[trow * 4 + 0][k0 + kc * 4];
      float4 a1 = *(const float4*)&a_lds[trow * 4 + 1][k0 + kc * 4];
      float4 a2 = *(const float4*)&a_lds[trow * 4 + 2][k0 + kc * 4];
      float4 a3 = *(const float4*)&a_lds[trow * 4 + 3][k0 + kc * 4];
      float4 b0 = *(const float4*)&b_lds[trow * 4 + 0][k0 + kc * 4];
      float4 b1 = *(const float4*)&b_lds[trow * 4 + 1][k0 + kc * 4];
      float4 b2 = *(const float4*)&b_lds[trow * 4 + 2][k0 + kc * 4];
      float4 b3 = *(const float4*)&b_lds[trow * 4 + 3][k0 + kc * 4];
#pragma unroll
      for (int kk = 0; kk < 4; ++kk) {
        float4 ws = *(const float4*)&ws_lds[kc * 4 + kk][tcol * 4];
        float4 wn = *(const float4*)&wn_lds[kc * 4 + kk][tcol * 4];
        float av0 = f4c(a0, kk), av1 = f4c(a1, kk), av2 = f4c(a2, kk), av3 = f4c(a3, kk);
        float bv0 = f4c(b0, kk), bv1 = f4c(b1, kk), bv2 = f4c(b2, kk), bv3 = f4c(b3, kk);
        acc[0][0] += av0 * ws.x; acc[0][1] += av0 * ws.y; acc[0][2] += av0 * ws.z; acc[0][3] += av0 * ws.w;
        acc[1][0] += av1 * ws.x; acc[1][1] += av1 * ws.y; acc[1][2] += av1 * ws.z; acc[1][3] += av1 * ws.w;
        acc[2][0] += av2 * ws.x; acc[2][1] += av2 * ws.y; acc[2][2] += av2 * ws.z; acc[2][3] += av2 * ws.w;
        acc[3][0] += av3 * ws.x; acc[3][1] += av3 * ws.y; acc[3][2] += av3 * ws.z; acc[3][3] += av3 * ws.w;
        acc[0][0] += bv0 * wn.x; acc[0][1] += bv0 * wn.y; acc[0][2] += bv0 * wn.z; acc[0][3] += bv0 * wn.w;
        acc[1][0] += bv1 * wn.x; acc[1][1] += bv1 * wn.y; acc[1][2] += bv1 * wn.z; acc[1][3] += bv1 * wn.w;
        acc[2][0] += bv2 * wn.x; acc[2][1] += bv2 * wn.y; acc[2][2] += bv2 * wn.z; acc[2][3] += bv2 * wn.w;
        acc[3][0] += bv3 * wn.x; acc[3][1] += bv3 * wn.y; acc[3][2] += bv3 * wn.z; acc[3][3] += bv3 * wn.w;
      }
    }
  }

  float4 bs  = *(const float4*)&bias[tcol * 4];
  float4 gv  = *(const float4*)&lg[tcol * 4];
  float4 bv2 = *(const float4*)&lb[tcol * 4];
#pragma unroll
  for (int r = 0; r < 4; ++r) {
    long row = base + trow * 4 + r;
    float4 o;
    o.x = acc[r][0] + bs.x; o.y = acc[r][1] + bs.y;
    o.z = acc[r][2] + bs.z; o.w = acc[r][3] + bs.w;
    if (row < n) *(float4*)&Hout[row * D + tcol * 4] = o;
    // residual: the staged A tile IS the node tile
    float4 av = *(const float4*)&a_lds[trow * 4 + r][tcol * 4];
    o.x += av.x; o.y += av.y; o.z += av.z; o.w += av.w;
    float s = o.x + o.y + o.z + o.w;
    float q = o.x * o.x + o.y * o.y + o.z * o.z + o.w * o.w;
#pragma unroll
    for (int m = 1; m < 32; m <<= 1) { s += __shfl_xor(s, m); q += __shfl_xor(q, m); }
    float mean = s * (1.f / 128.f);
    float var  = q * (1.f / 128.f) - mean * mean;
    float rs   = rsqrtf(fmaxf(var, 0.f) + 1e-5f);
    float4 y;
    y.x = fmaxf((o.x - mean) * rs * gv.x + bv2.x, 0.f);
    y.y = fmaxf((o.y - mean) * rs * gv.y + bv2.y, 0.f);
    y.z = fmaxf((o.z - mean) * rs * gv.z + bv2.z, 0.f);
    y.w = fmaxf((o.w - mean) * rs * gv.w + bv2.w, 0.f);
    if (row < n) *(float4*)&NodeOut[row * D + tcol * 4] = y;
  }
}

// ================= graph segment sum (batch sorted) =================
__global__ void k_gsum(const float* __restrict__ h,
                       const int* __restrict__ batch,
                       float* __restrict__ gacc, int n)
{
  const int d = threadIdx.x;                // 128 threads, one per dim
  int r0 = blockIdx.x * 256;
  int r1 = min(n, r0 + 256);
  if (r0 >= n) return;
  float acc = 0.f;
  int cur = batch[r0];
  for (int r = r0; r < r1; ++r) {
    int b = batch[r];
    if (b != cur) { atomicAdd(&gacc[cur * D + d], acc); acc = 0.f; cur = b; }
    acc += h[(long)r * D + d];
  }
  atomicAdd(&gacc[cur * D + d], acc);
}

// ================= graph LN: graph = LN(LN(gacc + graph)) =================
__global__ void k_ln_graph(const float* __restrict__ gacc,
                           float* __restrict__ graph,
                           const float* __restrict__ lg,
                           const float* __restrict__ lb)
{
  int row  = blockIdx.x;
  int lane = threadIdx.x;
  float2 gv = *(const float2*)&lg[lane * 2];
  float2 bv = *(const float2*)&lb[lane * 2];
  float2 a = *(const float2*)&gacc[row * D + lane * 2];
  float2 p = *(const float2*)&graph[row * D + lane * 2];
  float x0 = a.x + p.x, x1 = a.y + p.y;
#pragma unroll
  for (int pass = 0; pass < 2; ++pass) {
    float s = x0 + x1, q = x0 * x0 + x1 * x1;
#pragma unroll
    for (int m = 1; m < 64; m <<= 1) { s += __shfl_xor(s, m); q += __shfl_xor(q, m); }
    float mean = s * (1.f / 128.f);
    float var  = q * (1.f / 128.f) - mean * mean;
    float rs   = rsqrtf(fmaxf(var, 0.f) + 1e-5f);
    x0 = (x0 - mean) * rs * gv.x + bv.x;
    x1 = (x1 - mean) * rs * gv.y + bv.y;
  }
  float2 o; o.x = x0; o.y = x1;
  *(float2*)&graph[row * D + lane * 2] = o;
}

extern "C" void kernel_launch(void* const* d_in, const int* in_sizes, int n_in,
                              void* d_out, int out_size, void* d_ws, size_t ws_size,
                              hipStream_t stream)
{
  const float* x       = (const float*)d_in[0];
  const int*   edge    = (const int*)d_in[1];
  const int*   batch   = (const int*)d_in[2];
  const float* fc_w    = (const float*)d_in[3];
  const float* fc_b    = (const float*)d_in[4];
  const float* w_self  = (const float*)d_in[5];
  const float* w_neigh = (const float*)d_in[6];
  const float* conv_b  = (const float*)d_in[7];
  const float* ln_g    = (const float*)d_in[8];
  const float* ln_b    = (const float*)d_in[9];

  const int N = in_sizes[0] / D;
  const int E = in_sizes[1] / 2;
  const int* src = edge;
  const int* dst = edge + E;

  // ---- workspace layout ----
  int*   cnt      = (int*)d_ws;                 // N
  int*   rowptr   = cnt + N;                    // N
  int*   cursor   = rowptr + N;                 // N (ends as row-end)
  int*   bsum     = cursor + N;                 // 1024
  int*   csr_src  = bsum + 1024;                // E
  float* invdeg   = (float*)(csr_src + E);      // N
  float* gacc     = invdeg + N;                 // G*D
  float* graphbuf = gacc + NG * D;              // G*D
  float* nodebuf  = graphbuf + NG * D;          // N*D
  float* agg      = nodebuf + (long)N * D;      // N*D (alias: h)
  float* h        = agg;                        // GEMM raw output (in-place over agg)

  const int nb = (N + 1023) / 1024;

  hipMemsetAsync(cnt, 0, (size_t)N * sizeof(int), stream);
  hipMemsetAsync(graphbuf, 0, (size_t)NG * D * sizeof(float), stream);

  // ---- CSR build (once) ----
  k_count<<<2048, 256, 0, stream>>>(dst, cnt, E);
  k_invdeg<<<(N + 255) / 256, 256, 0, stream>>>(cnt, invdeg, N);
  k_blocksum<<<nb, 256, 0, stream>>>(cnt, bsum, N);
  k_scan_bsum<<<1, 1024, 0, stream>>>(bsum, nb);
  k_rowptr<<<nb, 256, 0, stream>>>(cnt, bsum, rowptr, cursor, N);
  k_fill<<<2048, 256, 0, stream>>>(src, dst, cursor, csr_src, E);

  // ---- input projection: nodebuf = x @ fc_w + fc_b ----
  k_proj<<<512, 256, 0, stream>>>(x, fc_w, fc_b, nodebuf, N);

  const int gblocks = (N + TILE_R - 1) / TILE_R;
  for (int l = 0; l < NL; ++l) {
    hipMemsetAsync(gacc, 0, (size_t)NG * D * sizeof(float), stream);
    k_aggr<<<(N + 3) / 4, 256, 0, stream>>>(nodebuf, rowptr, cursor, invdeg,
                                            csr_src, agg, N);
    // h (=agg in-place) gets raw conv output; nodebuf gets relu(LN(h+node))
    k_conv<<<gblocks, 256, 0, stream>>>(
        nodebuf, agg,
        w_self + (long)l * D * D, w_neigh + (long)l * D * D,
        conv_b + l * D, ln_g + l * D, ln_b + l * D,
        h, nodebuf, N);
    k_gsum<<<(N + 255) / 256, 128, 0, stream>>>(h, batch, gacc, N);
    k_ln_graph<<<NG, 64, 0, stream>>>(gacc, graphbuf, ln_g + l * D, ln_b + l * D);
  }

  // ---- single write of outputs ----
  hipMemcpyAsync(d_out, nodebuf, (size_t)N * D * sizeof(float),
                 hipMemcpyDeviceToDevice, stream);
  hipMemcpyAsync((float*)d_out + (long)N * D, graphbuf,
                 (size_t)NG * D * sizeof(float),
                 hipMemcpyDeviceToDevice, stream);
}

// Round 5
// 965.479 us; speedup vs baseline: 11.2012x; 1.5395x over previous
//
#include <hip/hip_runtime.h>

#define D 128
#define NG 64
#define NL 3

typedef __attribute__((ext_vector_type(8))) short bf16x8;
typedef __attribute__((ext_vector_type(4))) float f32x4;
typedef unsigned short u16;
typedef unsigned int   u32;

__device__ __forceinline__ float f4c(const float4& v, int i) {
  return i == 0 ? v.x : (i == 1 ? v.y : (i == 2 ? v.z : v.w));
}

__device__ __forceinline__ u16 f2bf(float x) {   // RNE
  u32 u = __float_as_uint(x);
  return (u16)((u + 0x7FFF + ((u >> 16) & 1)) >> 16);
}
__device__ __forceinline__ float bf2f(u16 b) {
  return __uint_as_float((u32)b << 16);
}

// ================= CSR build =================
__global__ void k_count(const int* __restrict__ dst, int* __restrict__ cnt, int E) {
  int i = blockIdx.x * blockDim.x + threadIdx.x;
  int stride = gridDim.x * blockDim.x;
  for (; i < E; i += stride) atomicAdd(&cnt[dst[i]], 1);
}

__global__ void k_invdeg(const int* __restrict__ cnt, float* __restrict__ invdeg, int n) {
  int i = blockIdx.x * blockDim.x + threadIdx.x;
  if (i < n) invdeg[i] = 1.0f / (float)max(cnt[i], 1);
}

__global__ void k_blocksum(const int* __restrict__ cnt, int* __restrict__ bsum, int n) {
  int b = blockIdx.x, t = threadIdx.x;
  int base = b * 1024 + t * 4;
  int s = 0;
#pragma unroll
  for (int j = 0; j < 4; ++j) if (base + j < n) s += cnt[base + j];
  int lane = t & 63, w = t >> 6;
#pragma unroll
  for (int m = 1; m < 64; m <<= 1) s += __shfl_xor(s, m);
  __shared__ int ws[4];
  if (lane == 0) ws[w] = s;
  __syncthreads();
  if (t == 0) bsum[b] = ws[0] + ws[1] + ws[2] + ws[3];
}

__global__ void k_scan_bsum(int* __restrict__ bsum, int nb) {
  __shared__ int s[1024];
  int t = threadIdx.x;
  int v = t < nb ? bsum[t] : 0;
  s[t] = v;
  __syncthreads();
  for (int off = 1; off < 1024; off <<= 1) {
    int x = (t >= off) ? s[t - off] : 0;
    __syncthreads();
    s[t] += x;
    __syncthreads();
  }
  if (t < nb) bsum[t] = s[t] - v;   // exclusive
}

__global__ void k_rowptr(const int* __restrict__ cnt, const int* __restrict__ bsum,
                         int* __restrict__ rowptr, int* __restrict__ cursor, int n) {
  int b = blockIdx.x, t = threadIdx.x;
  int base = b * 1024 + t * 4;
  int v0 = 0, v1 = 0, v2 = 0, v3 = 0;
  if (base + 0 < n) v0 = cnt[base + 0];
  if (base + 1 < n) v1 = cnt[base + 1];
  if (base + 2 < n) v2 = cnt[base + 2];
  if (base + 3 < n) v3 = cnt[base + 3];
  int ts = v0 + v1 + v2 + v3;
  int lane = t & 63, w = t >> 6;
  int incl = ts;
#pragma unroll
  for (int m = 1; m < 64; m <<= 1) {
    int o = __shfl_up(incl, m);
    if (lane >= m) incl += o;
  }
  __shared__ int wsum[4];
  if (lane == 63) wsum[w] = incl;
  __syncthreads();
  int woff = 0;
  for (int i = 0; i < w; ++i) woff += wsum[i];
  int run = incl - ts + woff + bsum[b];
  if (base + 0 < n) { rowptr[base + 0] = run; cursor[base + 0] = run; run += v0; }
  if (base + 1 < n) { rowptr[base + 1] = run; cursor[base + 1] = run; run += v1; }
  if (base + 2 < n) { rowptr[base + 2] = run; cursor[base + 2] = run; run += v2; }
  if (base + 3 < n) { rowptr[base + 3] = run; cursor[base + 3] = run; run += v3; }
}

__global__ void k_fill(const int* __restrict__ src, const int* __restrict__ dst,
                       int* __restrict__ cursor, int* __restrict__ csr_src, int E) {
  int i = blockIdx.x * blockDim.x + threadIdx.x;
  int stride = gridDim.x * blockDim.x;
  for (; i < E; i += stride) {
    int t = dst[i];
    int pos = atomicAdd(&cursor[t], 1);
    csr_src[pos] = src[i];
  }
}

// ================= weight prep: Wt[m][n][k] = bf16(W[m][k][n]) =================
__global__ void k_wprep(const float* __restrict__ W, u16* __restrict__ Wt, int nmats) {
  long idx = (long)blockIdx.x * blockDim.x + threadIdx.x;
  long total = (long)nmats * 16384;
  long stride = (long)gridDim.x * blockDim.x;
  for (; idx < total; idx += stride) {
    long m = idx >> 14;
    int o = (int)(idx & 16383);
    int nn = o >> 7, k = o & 127;
    Wt[idx] = f2bf(W[m * 16384 + k * 128 + nn]);
  }
}

// ================= aggregation: aggB[i] = bf16(mean_{e: dst=i} node[src[e]]) =========
__global__ void k_aggr(const u16* __restrict__ nodeB,
                       const int* __restrict__ rowptr, const int* __restrict__ rowend,
                       const float* __restrict__ invdeg,
                       const int* __restrict__ csr_src,
                       u16* __restrict__ aggB, int n) {
  int lane = threadIdx.x & 63;
  int w = (blockIdx.x * blockDim.x + threadIdx.x) >> 6;   // one wave per node
  if (w >= n) return;
  int s0 = rowptr[w], s1 = rowend[w];
  float a0 = 0.f, a1 = 0.f;
  for (int k = s0; k < s1; ++k) {
    int s = csr_src[k];
    u32 v = *(const u32*)&nodeB[(long)s * D + lane * 2];
    a0 += __uint_as_float(v << 16);
    a1 += __uint_as_float(v & 0xFFFF0000u);
  }
  float sc = invdeg[w];
  a0 *= sc; a1 *= sc;
  u32 packed = (u32)f2bf(a0) | ((u32)f2bf(a1) << 16);
  *(u32*)&aggB[(long)w * D + lane * 2] = packed;
}

// ================= projection: nodeB = bf16(X @ W + b)  (whole W in LDS) ============
__global__ __launch_bounds__(256, 2) void k_proj(
    const float* __restrict__ X, const float* __restrict__ W,
    const float* __restrict__ bias, u16* __restrict__ OutB, int n)
{
  __shared__ float w_lds[D * D];    // 64 KB, staged once
  __shared__ float xr[4][132];      // per-wave row buffer

  const int tid  = threadIdx.x;
  const int lane = tid & 63;
  const int w    = tid >> 6;

#pragma unroll
  for (int i = 0; i < 16; ++i) {
    int off = i * 1024 + tid * 4;
    *(float4*)&w_lds[off] = *(const float4*)&W[off];
  }
  __syncthreads();

  const float2 bs = *(const float2*)&bias[lane * 2];
  const int nwaves = gridDim.x * 4;

  for (int row = blockIdx.x * 4 + w; row < n; row += nwaves) {
    float2 xv = *(const float2*)&X[(long)row * D + lane * 2];
    *(float2*)&xr[w][lane * 2] = xv;          // wave-private buffer, no barrier
    float acc0 = bs.x, acc1 = bs.y;
#pragma unroll
    for (int k0 = 0; k0 < D; k0 += 4) {
      float4 xb = *(const float4*)&xr[w][k0]; // broadcast
#pragma unroll
      for (int kk = 0; kk < 4; ++kk) {
        float2 wv = *(const float2*)&w_lds[(k0 + kk) * D + lane * 2];
        float xs = f4c(xb, kk);
        acc0 += xs * wv.x;
        acc1 += xs * wv.y;
      }
    }
    u32 packed = (u32)f2bf(acc0) | ((u32)f2bf(acc1) << 16);
    *(u32*)&OutB[(long)row * D + lane * 2] = packed;
  }
}

// ================= MFMA conv: h = node@Ws + agg@Wn + b =================
// fused: gacc += segsum(h) ; node' = relu(LN(h + node)) [bf16, + fp32 on last layer]
__global__ __launch_bounds__(256) void k_conv_mfma(
    const u16* __restrict__ nodeB, const u16* __restrict__ aggB,
    const u16* __restrict__ WsT, const u16* __restrict__ WnT,   // [n][k] bf16
    const float* __restrict__ bias,
    const float* __restrict__ lg, const float* __restrict__ lb,
    const int* __restrict__ batch,
    float* __restrict__ gacc,
    u16* __restrict__ nodeOutB, float* __restrict__ nodeOutF,
    int n)
{
  __shared__ int batch_lds[64];
  const int tid  = threadIdx.x;
  const int lane = tid & 63;
  const int w    = tid >> 6;        // wave 0..3, owns rows w*16..w*16+15
  const int l15  = lane & 15;
  const int g    = lane >> 4;       // 0..3
  const long base = (long)blockIdx.x * 64;

  if (tid < 64) {
    long r = base + tid;
    batch_lds[tid] = batch[r < n ? r : (n - 1)];
  }
  __syncthreads();

  // ---- A fragments: row = l15 within wave tile, k-chunk = g*8 (+32 per kstep)
  long arow  = base + w * 16 + l15;
  long arowc = arow < n ? arow : (n - 1);

  bf16x8 aS[4], aA[4];
#pragma unroll
  for (int ks = 0; ks < 4; ++ks) {
    int k0 = ks * 32 + g * 8;
    aS[ks] = *(const bf16x8*)&nodeB[arowc * D + k0];
    aA[ks] = *(const bf16x8*)&aggB [arowc * D + k0];
  }

  f32x4 acc[8] = {};

#pragma unroll
  for (int f = 0; f < 8; ++f) {
    int nn = f * 16 + l15;
#pragma unroll
    for (int ks = 0; ks < 4; ++ks) {
      int k0 = ks * 32 + g * 8;
      bf16x8 bS = *(const bf16x8*)&WsT[nn * D + k0];
      bf16x8 bA = *(const bf16x8*)&WnT[nn * D + k0];
      acc[f] = __builtin_amdgcn_mfma_f32_16x16x32_bf16(aS[ks], bS, acc[f], 0, 0, 0);
      acc[f] = __builtin_amdgcn_mfma_f32_16x16x32_bf16(aA[ks], bA, acc[f], 0, 0, 0);
    }
  }

  // ---- epilogue params (col = f*16 + l15)
  float bs[8], lgv[8], lbv[8];
#pragma unroll
  for (int f = 0; f < 8; ++f) {
    bs[f]  = bias[f * 16 + l15];
    lgv[f] = lg[f * 16 + l15];
    lbv[f] = lb[f * 16 + l15];
  }

  // acc := h = conv + bias ; output rows: row_local = w*16 + g*4 + r
#pragma unroll
  for (int f = 0; f < 8; ++f)
#pragma unroll
    for (int r = 0; r < 4; ++r) acc[f][r] += bs[f];

  long rowb[4];
  bool valid[4];
#pragma unroll
  for (int r = 0; r < 4; ++r) {
    rowb[r]  = base + w * 16 + g * 4 + r;
    valid[r] = rowb[r] < n;
  }

  // ---- graph segment sum over this wave's 16 rows (batch sorted) ----
  const int wb = w * 16;
  int b_first = batch_lds[wb], b_last = batch_lds[wb + 15];
  if (b_first == b_last) {
#pragma unroll
    for (int f = 0; f < 8; ++f) {
      float ps = 0.f;
#pragma unroll
      for (int r = 0; r < 4; ++r) if (valid[r]) ps += acc[f][r];
      ps += __shfl_xor(ps, 16);
      ps += __shfl_xor(ps, 32);
      if (lane < 16) atomicAdd(&gacc[b_first * D + f * 16 + lane], ps);
    }
  } else {
    int i = 0;
    while (i < 16) {                    // wave-uniform (LDS scalars)
      int bseg = batch_lds[wb + i];
      int j = i + 1;
      while (j < 16 && batch_lds[wb + j] == bseg) ++j;
#pragma unroll
      for (int f = 0; f < 8; ++f) {
        float ps = 0.f;
#pragma unroll
        for (int r = 0; r < 4; ++r) {
          int lr = g * 4 + r;
          if (valid[r] && lr >= i && lr < j) ps += acc[f][r];
        }
        ps += __shfl_xor(ps, 16);
        ps += __shfl_xor(ps, 32);
        if (lane < 16) atomicAdd(&gacc[bseg * D + f * 16 + lane], ps);
      }
      i = j;
    }
  }

  // ---- residual + LN + relu ----
  float xv[8][4];
  float s[4] = {0, 0, 0, 0}, q[4] = {0, 0, 0, 0};
#pragma unroll
  for (int r = 0; r < 4; ++r) {
    long row = valid[r] ? rowb[r] : (n - 1);
#pragma unroll
    for (int f = 0; f < 8; ++f) {
      float nv = bf2f(nodeB[row * D + f * 16 + l15]);
      float x  = acc[f][r] + nv;
      xv[f][r] = x;
      s[r] += x; q[r] += x * x;
    }
  }
#pragma unroll
  for (int r = 0; r < 4; ++r) {
#pragma unroll
    for (int m = 1; m < 16; m <<= 1) {
      s[r] += __shfl_xor(s[r], m);
      q[r] += __shfl_xor(q[r], m);
    }
  }
#pragma unroll
  for (int r = 0; r < 4; ++r) {
    if (!valid[r]) continue;
    float mean = s[r] * (1.f / 128.f);
    float var  = q[r] * (1.f / 128.f) - mean * mean;
    float rs   = rsqrtf(fmaxf(var, 0.f) + 1e-5f);
#pragma unroll
    for (int f = 0; f < 8; ++f) {
      float y = fmaxf((xv[f][r] - mean) * rs * lgv[f] + lbv[f], 0.f);
      nodeOutB[rowb[r] * D + f * 16 + l15] = f2bf(y);
      if (nodeOutF) nodeOutF[rowb[r] * D + f * 16 + l15] = y;
    }
  }
}

// ================= graph LN: graph = LN(LN(gacc + graph)) =================
__global__ void k_ln_graph(const float* __restrict__ gacc,
                           float* __restrict__ graph,
                           const float* __restrict__ lg,
                           const float* __restrict__ lb)
{
  int row  = blockIdx.x;
  int lane = threadIdx.x;
  float2 gv = *(const float2*)&lg[lane * 2];
  float2 bv = *(const float2*)&lb[lane * 2];
  float2 a = *(const float2*)&gacc[row * D + lane * 2];
  float2 p = *(const float2*)&graph[row * D + lane * 2];
  float x0 = a.x + p.x, x1 = a.y + p.y;
#pragma unroll
  for (int pass = 0; pass < 2; ++pass) {
    float s = x0 + x1, q = x0 * x0 + x1 * x1;
#pragma unroll
    for (int m = 1; m < 64; m <<= 1) { s += __shfl_xor(s, m); q += __shfl_xor(q, m); }
    float mean = s * (1.f / 128.f);
    float var  = q * (1.f / 128.f) - mean * mean;
    float rs   = rsqrtf(fmaxf(var, 0.f) + 1e-5f);
    x0 = (x0 - mean) * rs * gv.x + bv.x;
    x1 = (x1 - mean) * rs * gv.y + bv.y;
  }
  float2 o; o.x = x0; o.y = x1;
  *(float2*)&graph[row * D + lane * 2] = o;
}

extern "C" void kernel_launch(void* const* d_in, const int* in_sizes, int n_in,
                              void* d_out, int out_size, void* d_ws, size_t ws_size,
                              hipStream_t stream)
{
  const float* x       = (const float*)d_in[0];
  const int*   edge    = (const int*)d_in[1];
  const int*   batch   = (const int*)d_in[2];
  const float* fc_w    = (const float*)d_in[3];
  const float* fc_b    = (const float*)d_in[4];
  const float* w_self  = (const float*)d_in[5];
  const float* w_neigh = (const float*)d_in[6];
  const float* conv_b  = (const float*)d_in[7];
  const float* ln_g    = (const float*)d_in[8];
  const float* ln_b    = (const float*)d_in[9];

  const int N = in_sizes[0] / D;
  const int E = in_sizes[1] / 2;
  const int* src = edge;
  const int* dst = edge + E;

  // ---- workspace layout ----
  int*   cnt      = (int*)d_ws;                 // N
  int*   rowptr   = cnt + N;                    // N
  int*   cursor   = rowptr + N;                 // N (ends as row-end)
  int*   bsum     = cursor + N;                 // 1024
  int*   csr_src  = bsum + 1024;                // E
  float* invdeg   = (float*)(csr_src + E);      // N
  float* gacc     = invdeg + N;                 // G*D
  float* graphbuf = gacc + NG * D;              // G*D
  // 16B-align the bf16 region
  char*  bfbase   = (char*)(graphbuf + NG * D);
  bfbase = (char*)(((size_t)bfbase + 15) & ~(size_t)15);
  u16*   nodeB    = (u16*)bfbase;               // N*D bf16
  u16*   aggB     = nodeB + (long)N * D;        // N*D bf16
  u16*   wsT      = aggB + (long)N * D;         // 3*128*128 bf16
  u16*   wnT      = wsT + 3 * D * D;            // 3*128*128 bf16

  const int nb = (N + 1023) / 1024;

  hipMemsetAsync(cnt, 0, (size_t)N * sizeof(int), stream);
  hipMemsetAsync(graphbuf, 0, (size_t)NG * D * sizeof(float), stream);

  // ---- CSR build (once) ----
  k_count<<<2048, 256, 0, stream>>>(dst, cnt, E);
  k_invdeg<<<(N + 255) / 256, 256, 0, stream>>>(cnt, invdeg, N);
  k_blocksum<<<nb, 256, 0, stream>>>(cnt, bsum, N);
  k_scan_bsum<<<1, 1024, 0, stream>>>(bsum, nb);
  k_rowptr<<<nb, 256, 0, stream>>>(cnt, bsum, rowptr, cursor, N);
  k_fill<<<2048, 256, 0, stream>>>(src, dst, cursor, csr_src, E);

  // ---- weight prep (bf16, transposed to [n][k]) ----
  k_wprep<<<192, 256, 0, stream>>>(w_self,  wsT, NL);
  k_wprep<<<192, 256, 0, stream>>>(w_neigh, wnT, NL);

  // ---- input projection: nodeB = bf16(x @ fc_w + fc_b) ----
  k_proj<<<512, 256, 0, stream>>>(x, fc_w, fc_b, nodeB, N);

  const int cblocks = (N + 63) / 64;
  for (int l = 0; l < NL; ++l) {
    hipMemsetAsync(gacc, 0, (size_t)NG * D * sizeof(float), stream);
    k_aggr<<<(N + 3) / 4, 256, 0, stream>>>(nodeB, rowptr, cursor, invdeg,
                                            csr_src, aggB, N);
    k_conv_mfma<<<cblocks, 256, 0, stream>>>(
        nodeB, aggB, wsT + (long)l * D * D, wnT + (long)l * D * D,
        conv_b + l * D, ln_g + l * D, ln_b + l * D,
        batch, gacc,
        nodeB, (l == NL - 1) ? (float*)d_out : nullptr, N);
    k_ln_graph<<<NG, 64, 0, stream>>>(gacc, graphbuf, ln_g + l * D, ln_b + l * D);
  }

  // ---- graph output ----
  hipMemcpyAsync((float*)d_out + (long)N * D, graphbuf,
                 (size_t)NG * D * sizeof(float),
                 hipMemcpyDeviceToDevice, stream);
}

// Round 6
// 668.505 us; speedup vs baseline: 16.1772x; 1.4442x over previous
//
#include <hip/hip_runtime.h>

#define D 128
#define NG 64
#define NL 3

typedef __attribute__((ext_vector_type(8))) short bf16x8;
typedef __attribute__((ext_vector_type(4))) float f32x4;
typedef unsigned short u16;
typedef unsigned int   u32;

__device__ __forceinline__ float f4c(const float4& v, int i) {
  return i == 0 ? v.x : (i == 1 ? v.y : (i == 2 ? v.z : v.w));
}

__device__ __forceinline__ u16 f2bf(float x) {   // RNE
  u32 u = __float_as_uint(x);
  return (u16)((u + 0x7FFF + ((u >> 16) & 1)) >> 16);
}
__device__ __forceinline__ float bf2f(u16 b) {
  return __uint_as_float((u32)b << 16);
}

// ================= CSR build =================
__global__ void k_count(const int* __restrict__ dst, int* __restrict__ cnt, int E) {
  int i = blockIdx.x * blockDim.x + threadIdx.x;
  int stride = gridDim.x * blockDim.x;
  for (; i < E; i += stride) atomicAdd(&cnt[dst[i]], 1);
}

__global__ void k_invdeg(const int* __restrict__ cnt, float* __restrict__ invdeg, int n) {
  int i = blockIdx.x * blockDim.x + threadIdx.x;
  if (i < n) invdeg[i] = 1.0f / (float)max(cnt[i], 1);
}

__global__ void k_blocksum(const int* __restrict__ cnt, int* __restrict__ bsum, int n) {
  int b = blockIdx.x, t = threadIdx.x;
  int base = b * 1024 + t * 4;
  int s = 0;
#pragma unroll
  for (int j = 0; j < 4; ++j) if (base + j < n) s += cnt[base + j];
  int lane = t & 63, w = t >> 6;
#pragma unroll
  for (int m = 1; m < 64; m <<= 1) s += __shfl_xor(s, m);
  __shared__ int ws[4];
  if (lane == 0) ws[w] = s;
  __syncthreads();
  if (t == 0) bsum[b] = ws[0] + ws[1] + ws[2] + ws[3];
}

__global__ void k_scan_bsum(int* __restrict__ bsum, int nb) {
  __shared__ int s[1024];
  int t = threadIdx.x;
  int v = t < nb ? bsum[t] : 0;
  s[t] = v;
  __syncthreads();
  for (int off = 1; off < 1024; off <<= 1) {
    int x = (t >= off) ? s[t - off] : 0;
    __syncthreads();
    s[t] += x;
    __syncthreads();
  }
  if (t < nb) bsum[t] = s[t] - v;   // exclusive
}

__global__ void k_rowptr(const int* __restrict__ cnt, const int* __restrict__ bsum,
                         int* __restrict__ rowptr, int* __restrict__ cursor, int n) {
  int b = blockIdx.x, t = threadIdx.x;
  int base = b * 1024 + t * 4;
  int v0 = 0, v1 = 0, v2 = 0, v3 = 0;
  if (base + 0 < n) v0 = cnt[base + 0];
  if (base + 1 < n) v1 = cnt[base + 1];
  if (base + 2 < n) v2 = cnt[base + 2];
  if (base + 3 < n) v3 = cnt[base + 3];
  int ts = v0 + v1 + v2 + v3;
  int lane = t & 63, w = t >> 6;
  int incl = ts;
#pragma unroll
  for (int m = 1; m < 64; m <<= 1) {
    int o = __shfl_up(incl, m);
    if (lane >= m) incl += o;
  }
  __shared__ int wsum[4];
  if (lane == 63) wsum[w] = incl;
  __syncthreads();
  int woff = 0;
  for (int i = 0; i < w; ++i) woff += wsum[i];
  int run = incl - ts + woff + bsum[b];
  if (base + 0 < n) { rowptr[base + 0] = run; cursor[base + 0] = run; run += v0; }
  if (base + 1 < n) { rowptr[base + 1] = run; cursor[base + 1] = run; run += v1; }
  if (base + 2 < n) { rowptr[base + 2] = run; cursor[base + 2] = run; run += v2; }
  if (base + 3 < n) { rowptr[base + 3] = run; cursor[base + 3] = run; run += v3; }
}

__global__ void k_fill(const int* __restrict__ src, const int* __restrict__ dst,
                       int* __restrict__ cursor, int* __restrict__ csr_src, int E) {
  int i = blockIdx.x * blockDim.x + threadIdx.x;
  int stride = gridDim.x * blockDim.x;
  for (; i < E; i += stride) {
    int t = dst[i];
    int pos = atomicAdd(&cursor[t], 1);
    csr_src[pos] = src[i];
  }
}

// ================= weight prep: Wt[m][n][k] = bf16(W[m][k][n]) =================
__global__ void k_wprep(const float* __restrict__ W, u16* __restrict__ Wt, int nmats) {
  long idx = (long)blockIdx.x * blockDim.x + threadIdx.x;
  long total = (long)nmats * 16384;
  long stride = (long)gridDim.x * blockDim.x;
  for (; idx < total; idx += stride) {
    long m = idx >> 14;
    int o = (int)(idx & 16383);
    int nn = o >> 7, k = o & 127;
    Wt[idx] = f2bf(W[m * 16384 + k * 128 + nn]);
  }
}

// ================= aggregation: aggB[i] = bf16(mean_{e: dst=i} node[src[e]]) =========
// 16-lane group per node (4 nodes/wave); lane reads bf16x8 (16B) chunk of each row.
// CSR indices preloaded 16-at-a-time + shfl broadcast; 4 independent gathers in flight.
__global__ void k_aggr(const u16* __restrict__ nodeB,
                       const int* __restrict__ rowptr, const int* __restrict__ rowend,
                       const float* __restrict__ invdeg,
                       const int* __restrict__ csr_src,
                       u16* __restrict__ aggB, int n) {
  const int tid  = threadIdx.x;
  const int lane = tid & 63;
  const int l15  = lane & 15;
  const int g    = lane >> 4;                               // group 0..3
  const int wav  = (blockIdx.x * blockDim.x + tid) >> 6;
  const int node = wav * 4 + g;
  if (node >= n) return;

  const int s0 = rowptr[node];
  const int nk = rowend[node] - s0;
  const long off = (long)l15 * 8;                           // 8 bf16 per lane

  float acc[8] = {};

  for (int kb = 0; kb < nk; kb += 16) {
    const int rem = min(16, nk - kb);
    int myidx = (l15 < rem) ? csr_src[s0 + kb + l15] : 0;   // 64B coalesced per group
    int kk = 0;
    for (; kk + 4 <= rem; kk += 4) {
      bf16x8 v[4];
#pragma unroll
      for (int j = 0; j < 4; ++j) {
        int s = __shfl(myidx, (g << 4) + kk + j);           // in-register broadcast
        v[j] = *(const bf16x8*)&nodeB[(long)s * D + off];   // 4 independent gathers
      }
#pragma unroll
      for (int j = 0; j < 4; ++j)
#pragma unroll
        for (int e = 0; e < 8; ++e)
          acc[e] += bf2f((u16)v[j][e]);
    }
    for (; kk < rem; ++kk) {
      int s = __shfl(myidx, (g << 4) + kk);
      bf16x8 v = *(const bf16x8*)&nodeB[(long)s * D + off];
#pragma unroll
      for (int e = 0; e < 8; ++e) acc[e] += bf2f((u16)v[e]);
    }
  }

  const float sc = invdeg[node];
  bf16x8 ov;
#pragma unroll
  for (int e = 0; e < 8; ++e) ov[e] = (short)f2bf(acc[e] * sc);
  *(bf16x8*)&aggB[(long)node * D + off] = ov;               // 16B coalesced store
}

// ================= projection: nodeB = bf16(X @ W + b)  (whole W in LDS) ============
__global__ __launch_bounds__(256, 2) void k_proj(
    const float* __restrict__ X, const float* __restrict__ W,
    const float* __restrict__ bias, u16* __restrict__ OutB, int n)
{
  __shared__ float w_lds[D * D];    // 64 KB, staged once
  __shared__ float xr[4][132];      // per-wave row buffer

  const int tid  = threadIdx.x;
  const int lane = tid & 63;
  const int w    = tid >> 6;

#pragma unroll
  for (int i = 0; i < 16; ++i) {
    int off = i * 1024 + tid * 4;
    *(float4*)&w_lds[off] = *(const float4*)&W[off];
  }
  __syncthreads();

  const float2 bs = *(const float2*)&bias[lane * 2];
  const int nwaves = gridDim.x * 4;

  for (int row = blockIdx.x * 4 + w; row < n; row += nwaves) {
    float2 xv = *(const float2*)&X[(long)row * D + lane * 2];
    *(float2*)&xr[w][lane * 2] = xv;          // wave-private buffer, no barrier
    float acc0 = bs.x, acc1 = bs.y;
#pragma unroll
    for (int k0 = 0; k0 < D; k0 += 4) {
      float4 xb = *(const float4*)&xr[w][k0]; // broadcast
#pragma unroll
      for (int kk = 0; kk < 4; ++kk) {
        float2 wv = *(const float2*)&w_lds[(k0 + kk) * D + lane * 2];
        float xs = f4c(xb, kk);
        acc0 += xs * wv.x;
        acc1 += xs * wv.y;
      }
    }
    u32 packed = (u32)f2bf(acc0) | ((u32)f2bf(acc1) << 16);
    *(u32*)&OutB[(long)row * D + lane * 2] = packed;
  }
}

// ================= MFMA conv: h = node@Ws + agg@Wn + b =================
// fused: gacc += segsum(h) ; node' = relu(LN(h + node)) [bf16, + fp32 on last layer]
__global__ __launch_bounds__(256) void k_conv_mfma(
    const u16* __restrict__ nodeB, const u16* __restrict__ aggB,
    const u16* __restrict__ WsT, const u16* __restrict__ WnT,   // [n][k] bf16
    const float* __restrict__ bias,
    const float* __restrict__ lg, const float* __restrict__ lb,
    const int* __restrict__ batch,
    float* __restrict__ gacc,
    u16* __restrict__ nodeOutB, float* __restrict__ nodeOutF,
    int n)
{
  __shared__ int batch_lds[64];
  const int tid  = threadIdx.x;
  const int lane = tid & 63;
  const int w    = tid >> 6;        // wave 0..3, owns rows w*16..w*16+15
  const int l15  = lane & 15;
  const int g    = lane >> 4;       // 0..3
  const long base = (long)blockIdx.x * 64;

  if (tid < 64) {
    long r = base + tid;
    batch_lds[tid] = batch[r < n ? r : (n - 1)];
  }
  __syncthreads();

  // ---- A fragments: row = l15 within wave tile, k-chunk = g*8 (+32 per kstep)
  long arow  = base + w * 16 + l15;
  long arowc = arow < n ? arow : (n - 1);

  bf16x8 aS[4], aA[4];
#pragma unroll
  for (int ks = 0; ks < 4; ++ks) {
    int k0 = ks * 32 + g * 8;
    aS[ks] = *(const bf16x8*)&nodeB[arowc * D + k0];
    aA[ks] = *(const bf16x8*)&aggB [arowc * D + k0];
  }

  f32x4 acc[8] = {};

#pragma unroll
  for (int f = 0; f < 8; ++f) {
    int nn = f * 16 + l15;
#pragma unroll
    for (int ks = 0; ks < 4; ++ks) {
      int k0 = ks * 32 + g * 8;
      bf16x8 bS = *(const bf16x8*)&WsT[nn * D + k0];
      bf16x8 bA = *(const bf16x8*)&WnT[nn * D + k0];
      acc[f] = __builtin_amdgcn_mfma_f32_16x16x32_bf16(aS[ks], bS, acc[f], 0, 0, 0);
      acc[f] = __builtin_amdgcn_mfma_f32_16x16x32_bf16(aA[ks], bA, acc[f], 0, 0, 0);
    }
  }

  // ---- epilogue params (col = f*16 + l15)
  float bs[8], lgv[8], lbv[8];
#pragma unroll
  for (int f = 0; f < 8; ++f) {
    bs[f]  = bias[f * 16 + l15];
    lgv[f] = lg[f * 16 + l15];
    lbv[f] = lb[f * 16 + l15];
  }

  // acc := h = conv + bias ; output rows: row_local = w*16 + g*4 + r
#pragma unroll
  for (int f = 0; f < 8; ++f)
#pragma unroll
    for (int r = 0; r < 4; ++r) acc[f][r] += bs[f];

  long rowb[4];
  bool valid[4];
#pragma unroll
  for (int r = 0; r < 4; ++r) {
    rowb[r]  = base + w * 16 + g * 4 + r;
    valid[r] = rowb[r] < n;
  }

  // ---- graph segment sum over this wave's 16 rows (batch sorted) ----
  const int wb = w * 16;
  int b_first = batch_lds[wb], b_last = batch_lds[wb + 15];
  if (b_first == b_last) {
#pragma unroll
    for (int f = 0; f < 8; ++f) {
      float ps = 0.f;
#pragma unroll
      for (int r = 0; r < 4; ++r) if (valid[r]) ps += acc[f][r];
      ps += __shfl_xor(ps, 16);
      ps += __shfl_xor(ps, 32);
      if (lane < 16) atomicAdd(&gacc[b_first * D + f * 16 + lane], ps);
    }
  } else {
    int i = 0;
    while (i < 16) {                    // wave-uniform (LDS scalars)
      int bseg = batch_lds[wb + i];
      int j = i + 1;
      while (j < 16 && batch_lds[wb + j] == bseg) ++j;
#pragma unroll
      for (int f = 0; f < 8; ++f) {
        float ps = 0.f;
#pragma unroll
        for (int r = 0; r < 4; ++r) {
          int lr = g * 4 + r;
          if (valid[r] && lr >= i && lr < j) ps += acc[f][r];
        }
        ps += __shfl_xor(ps, 16);
        ps += __shfl_xor(ps, 32);
        if (lane < 16) atomicAdd(&gacc[bseg * D + f * 16 + lane], ps);
      }
      i = j;
    }
  }

  // ---- residual + LN + relu ----
  float xv[8][4];
  float s[4] = {0, 0, 0, 0}, q[4] = {0, 0, 0, 0};
#pragma unroll
  for (int r = 0; r < 4; ++r) {
    long row = valid[r] ? rowb[r] : (n - 1);
#pragma unroll
    for (int f = 0; f < 8; ++f) {
      float nv = bf2f(nodeB[row * D + f * 16 + l15]);
      float x  = acc[f][r] + nv;
      xv[f][r] = x;
      s[r] += x; q[r] += x * x;
    }
  }
#pragma unroll
  for (int r = 0; r < 4; ++r) {
#pragma unroll
    for (int m = 1; m < 16; m <<= 1) {
      s[r] += __shfl_xor(s[r], m);
      q[r] += __shfl_xor(q[r], m);
    }
  }
#pragma unroll
  for (int r = 0; r < 4; ++r) {
    if (!valid[r]) continue;
    float mean = s[r] * (1.f / 128.f);
    float var  = q[r] * (1.f / 128.f) - mean * mean;
    float rs   = rsqrtf(fmaxf(var, 0.f) + 1e-5f);
#pragma unroll
    for (int f = 0; f < 8; ++f) {
      float y = fmaxf((xv[f][r] - mean) * rs * lgv[f] + lbv[f], 0.f);
      nodeOutB[rowb[r] * D + f * 16 + l15] = f2bf(y);
      if (nodeOutF) nodeOutF[rowb[r] * D + f * 16 + l15] = y;
    }
  }
}

// ================= graph LN: graph = LN(LN(gacc + graph)) =================
__global__ void k_ln_graph(const float* __restrict__ gacc,
                           float* __restrict__ graph,
                           const float* __restrict__ lg,
                           const float* __restrict__ lb)
{
  int row  = blockIdx.x;
  int lane = threadIdx.x;
  float2 gv = *(const float2*)&lg[lane * 2];
  float2 bv = *(const float2*)&lb[lane * 2];
  float2 a = *(const float2*)&gacc[row * D + lane * 2];
  float2 p = *(const float2*)&graph[row * D + lane * 2];
  float x0 = a.x + p.x, x1 = a.y + p.y;
#pragma unroll
  for (int pass = 0; pass < 2; ++pass) {
    float s = x0 + x1, q = x0 * x0 + x1 * x1;
#pragma unroll
    for (int m = 1; m < 64; m <<= 1) { s += __shfl_xor(s, m); q += __shfl_xor(q, m); }
    float mean = s * (1.f / 128.f);
    float var  = q * (1.f / 128.f) - mean * mean;
    float rs   = rsqrtf(fmaxf(var, 0.f) + 1e-5f);
    x0 = (x0 - mean) * rs * gv.x + bv.x;
    x1 = (x1 - mean) * rs * gv.y + bv.y;
  }
  float2 o; o.x = x0; o.y = x1;
  *(float2*)&graph[row * D + lane * 2] = o;
}

extern "C" void kernel_launch(void* const* d_in, const int* in_sizes, int n_in,
                              void* d_out, int out_size, void* d_ws, size_t ws_size,
                              hipStream_t stream)
{
  const float* x       = (const float*)d_in[0];
  const int*   edge    = (const int*)d_in[1];
  const int*   batch   = (const int*)d_in[2];
  const float* fc_w    = (const float*)d_in[3];
  const float* fc_b    = (const float*)d_in[4];
  const float* w_self  = (const float*)d_in[5];
  const float* w_neigh = (const float*)d_in[6];
  const float* conv_b  = (const float*)d_in[7];
  const float* ln_g    = (const float*)d_in[8];
  const float* ln_b    = (const float*)d_in[9];

  const int N = in_sizes[0] / D;
  const int E = in_sizes[1] / 2;
  const int* src = edge;
  const int* dst = edge + E;

  // ---- workspace layout ----
  int*   cnt      = (int*)d_ws;                 // N
  int*   rowptr   = cnt + N;                    // N
  int*   cursor   = rowptr + N;                 // N (ends as row-end)
  int*   bsum     = cursor + N;                 // 1024
  int*   csr_src  = bsum + 1024;                // E
  float* invdeg   = (float*)(csr_src + E);      // N
  float* gacc     = invdeg + N;                 // G*D
  float* graphbuf = gacc + NG * D;              // G*D
  // 16B-align the bf16 region
  char*  bfbase   = (char*)(graphbuf + NG * D);
  bfbase = (char*)(((size_t)bfbase + 15) & ~(size_t)15);
  u16*   nodeB    = (u16*)bfbase;               // N*D bf16
  u16*   aggB     = nodeB + (long)N * D;        // N*D bf16
  u16*   wsT      = aggB + (long)N * D;         // 3*128*128 bf16
  u16*   wnT      = wsT + 3 * D * D;            // 3*128*128 bf16

  const int nb = (N + 1023) / 1024;

  hipMemsetAsync(cnt, 0, (size_t)N * sizeof(int), stream);
  hipMemsetAsync(graphbuf, 0, (size_t)NG * D * sizeof(float), stream);

  // ---- CSR build (once) ----
  k_count<<<2048, 256, 0, stream>>>(dst, cnt, E);
  k_invdeg<<<(N + 255) / 256, 256, 0, stream>>>(cnt, invdeg, N);
  k_blocksum<<<nb, 256, 0, stream>>>(cnt, bsum, N);
  k_scan_bsum<<<1, 1024, 0, stream>>>(bsum, nb);
  k_rowptr<<<nb, 256, 0, stream>>>(cnt, bsum, rowptr, cursor, N);
  k_fill<<<2048, 256, 0, stream>>>(src, dst, cursor, csr_src, E);

  // ---- weight prep (bf16, transposed to [n][k]) ----
  k_wprep<<<192, 256, 0, stream>>>(w_self,  wsT, NL);
  k_wprep<<<192, 256, 0, stream>>>(w_neigh, wnT, NL);

  // ---- input projection: nodeB = bf16(x @ fc_w + fc_b) ----
  k_proj<<<512, 256, 0, stream>>>(x, fc_w, fc_b, nodeB, N);

  const int cblocks = (N + 63) / 64;
  const int ablocks = (N + 15) / 16;
  for (int l = 0; l < NL; ++l) {
    hipMemsetAsync(gacc, 0, (size_t)NG * D * sizeof(float), stream);
    k_aggr<<<ablocks, 256, 0, stream>>>(nodeB, rowptr, cursor, invdeg,
                                        csr_src, aggB, N);
    k_conv_mfma<<<cblocks, 256, 0, stream>>>(
        nodeB, aggB, wsT + (long)l * D * D, wnT + (long)l * D * D,
        conv_b + l * D, ln_g + l * D, ln_b + l * D,
        batch, gacc,
        nodeB, (l == NL - 1) ? (float*)d_out : nullptr, N);
    k_ln_graph<<<NG, 64, 0, stream>>>(gacc, graphbuf, ln_g + l * D, ln_b + l * D);
  }

  // ---- graph output ----
  hipMemcpyAsync((float*)d_out + (long)N * D, graphbuf,
                 (size_t)NG * D * sizeof(float),
                 hipMemcpyDeviceToDevice, stream);
}

// Round 7
// 630.924 us; speedup vs baseline: 17.1408x; 1.0596x over previous
//
#include <hip/hip_runtime.h>

#define D 128
#define NG 64
#define NL 3
#define NPART 8

typedef __attribute__((ext_vector_type(8))) short bf16x8;
typedef __attribute__((ext_vector_type(4))) float f32x4;
typedef unsigned short u16;
typedef unsigned int   u32;

__device__ __forceinline__ float f4c(const float4& v, int i) {
  return i == 0 ? v.x : (i == 1 ? v.y : (i == 2 ? v.z : v.w));
}

__device__ __forceinline__ u16 f2bf(float x) {   // RNE
  u32 u = __float_as_uint(x);
  return (u16)((u + 0x7FFF + ((u >> 16) & 1)) >> 16);
}
__device__ __forceinline__ float bf2f(u16 b) {
  return __uint_as_float((u32)b << 16);
}

// ================= CSR build (XCD-partitioned by dst range) =================
// blockIdx.x % 8 ~ XCD id; partition p owns dst in [p*psize, (p+1)*psize).
// All atomics + scattered writes for a partition stay in one XCD's L2.
__global__ void k_count(const int* __restrict__ dst, int* __restrict__ cnt,
                        int E, int psize) {
  const int myp = blockIdx.x & (NPART - 1);
  const int lo  = myp * psize, hi = lo + psize;
  const int tpp = (gridDim.x / NPART) * blockDim.x;        // threads per partition
  int i = (blockIdx.x >> 3) * blockDim.x + threadIdx.x;
  for (; i < E; i += tpp) {
    int t = dst[i];
    if (t >= lo && t < hi) atomicAdd(&cnt[t], 1);
  }
}

__global__ void k_fill(const int* __restrict__ src, const int* __restrict__ dst,
                       int* __restrict__ cursor, int* __restrict__ csr_src,
                       int E, int psize) {
  const int myp = blockIdx.x & (NPART - 1);
  const int lo  = myp * psize, hi = lo + psize;
  const int tpp = (gridDim.x / NPART) * blockDim.x;
  int i = (blockIdx.x >> 3) * blockDim.x + threadIdx.x;
  for (; i < E; i += tpp) {
    int t = dst[i];
    int s = src[i];                                        // coalesced, L3-served
    if (t >= lo && t < hi) {
      int pos = atomicAdd(&cursor[t], 1);
      csr_src[pos] = s;
    }
  }
}

__global__ void k_invdeg(const int* __restrict__ cnt, float* __restrict__ invdeg, int n) {
  int i = blockIdx.x * blockDim.x + threadIdx.x;
  if (i < n) invdeg[i] = 1.0f / (float)max(cnt[i], 1);
}

__global__ void k_blocksum(const int* __restrict__ cnt, int* __restrict__ bsum, int n) {
  int b = blockIdx.x, t = threadIdx.x;
  int base = b * 1024 + t * 4;
  int s = 0;
#pragma unroll
  for (int j = 0; j < 4; ++j) if (base + j < n) s += cnt[base + j];
  int lane = t & 63, w = t >> 6;
#pragma unroll
  for (int m = 1; m < 64; m <<= 1) s += __shfl_xor(s, m);
  __shared__ int ws[4];
  if (lane == 0) ws[w] = s;
  __syncthreads();
  if (t == 0) bsum[b] = ws[0] + ws[1] + ws[2] + ws[3];
}

__global__ void k_scan_bsum(int* __restrict__ bsum, int nb) {
  __shared__ int s[1024];
  int t = threadIdx.x;
  int v = t < nb ? bsum[t] : 0;
  s[t] = v;
  __syncthreads();
  for (int off = 1; off < 1024; off <<= 1) {
    int x = (t >= off) ? s[t - off] : 0;
    __syncthreads();
    s[t] += x;
    __syncthreads();
  }
  if (t < nb) bsum[t] = s[t] - v;   // exclusive
}

__global__ void k_rowptr(const int* __restrict__ cnt, const int* __restrict__ bsum,
                         int* __restrict__ rowptr, int* __restrict__ cursor, int n) {
  int b = blockIdx.x, t = threadIdx.x;
  int base = b * 1024 + t * 4;
  int v0 = 0, v1 = 0, v2 = 0, v3 = 0;
  if (base + 0 < n) v0 = cnt[base + 0];
  if (base + 1 < n) v1 = cnt[base + 1];
  if (base + 2 < n) v2 = cnt[base + 2];
  if (base + 3 < n) v3 = cnt[base + 3];
  int ts = v0 + v1 + v2 + v3;
  int lane = t & 63, w = t >> 6;
  int incl = ts;
#pragma unroll
  for (int m = 1; m < 64; m <<= 1) {
    int o = __shfl_up(incl, m);
    if (lane >= m) incl += o;
  }
  __shared__ int wsum[4];
  if (lane == 63) wsum[w] = incl;
  __syncthreads();
  int woff = 0;
  for (int i = 0; i < w; ++i) woff += wsum[i];
  int run = incl - ts + woff + bsum[b];
  if (base + 0 < n) { rowptr[base + 0] = run; cursor[base + 0] = run; run += v0; }
  if (base + 1 < n) { rowptr[base + 1] = run; cursor[base + 1] = run; run += v1; }
  if (base + 2 < n) { rowptr[base + 2] = run; cursor[base + 2] = run; run += v2; }
  if (base + 3 < n) { rowptr[base + 3] = run; cursor[base + 3] = run; run += v3; }
}

// ================= weight prep: Wt[m][n][k] = bf16(W[m][k][n]) =================
__global__ void k_wprep(const float* __restrict__ W, u16* __restrict__ Wt, int nmats) {
  long idx = (long)blockIdx.x * blockDim.x + threadIdx.x;
  long total = (long)nmats * 16384;
  long stride = (long)gridDim.x * blockDim.x;
  for (; idx < total; idx += stride) {
    long m = idx >> 14;
    int o = (int)(idx & 16383);
    int nn = o >> 7, k = o & 127;
    Wt[idx] = f2bf(W[m * 16384 + k * 128 + nn]);
  }
}

// ================= aggregation: aggB[i] = bf16(mean_{e: dst=i} node[src[e]]) =========
// 16-lane group per node (4 nodes/wave); lane reads bf16x8 (16B) chunk of each row.
// CSR indices preloaded 16-at-a-time + shfl broadcast; 8 independent gathers in flight.
__global__ void k_aggr(const u16* __restrict__ nodeB,
                       const int* __restrict__ rowptr, const int* __restrict__ rowend,
                       const float* __restrict__ invdeg,
                       const int* __restrict__ csr_src,
                       u16* __restrict__ aggB, int n) {
  const int tid  = threadIdx.x;
  const int lane = tid & 63;
  const int l15  = lane & 15;
  const int g    = lane >> 4;                               // group 0..3
  const int wav  = (blockIdx.x * blockDim.x + tid) >> 6;
  const int node = wav * 4 + g;
  if (node >= n) return;

  const int s0 = rowptr[node];
  const int nk = rowend[node] - s0;
  const long off = (long)l15 * 8;                           // 8 bf16 per lane

  float acc[8] = {};

  for (int kb = 0; kb < nk; kb += 16) {
    const int rem = min(16, nk - kb);
    int myidx = (l15 < rem) ? csr_src[s0 + kb + l15] : 0;   // 64B coalesced per group
    int kk = 0;
    for (; kk + 8 <= rem; kk += 8) {
      bf16x8 v[8];
#pragma unroll
      for (int j = 0; j < 8; ++j) {
        int s = __shfl(myidx, (g << 4) + kk + j);           // in-register broadcast
        v[j] = *(const bf16x8*)&nodeB[(long)s * D + off];   // 8 independent gathers
      }
#pragma unroll
      for (int j = 0; j < 8; ++j)
#pragma unroll
        for (int e = 0; e < 8; ++e)
          acc[e] += bf2f((u16)v[j][e]);
    }
    for (; kk + 4 <= rem; kk += 4) {
      bf16x8 v[4];
#pragma unroll
      for (int j = 0; j < 4; ++j) {
        int s = __shfl(myidx, (g << 4) + kk + j);
        v[j] = *(const bf16x8*)&nodeB[(long)s * D + off];
      }
#pragma unroll
      for (int j = 0; j < 4; ++j)
#pragma unroll
        for (int e = 0; e < 8; ++e)
          acc[e] += bf2f((u16)v[j][e]);
    }
    for (; kk < rem; ++kk) {
      int s = __shfl(myidx, (g << 4) + kk);
      bf16x8 v = *(const bf16x8*)&nodeB[(long)s * D + off];
#pragma unroll
      for (int e = 0; e < 8; ++e) acc[e] += bf2f((u16)v[e]);
    }
  }

  const float sc = invdeg[node];
  bf16x8 ov;
#pragma unroll
  for (int e = 0; e < 8; ++e) ov[e] = (short)f2bf(acc[e] * sc);
  *(bf16x8*)&aggB[(long)node * D + off] = ov;               // 16B coalesced store
}

// ================= projection: nodeB = bf16(X @ W + b)  (whole W in LDS) ============
__global__ __launch_bounds__(256, 2) void k_proj(
    const float* __restrict__ X, const float* __restrict__ W,
    const float* __restrict__ bias, u16* __restrict__ OutB, int n)
{
  __shared__ float w_lds[D * D];    // 64 KB, staged once
  __shared__ float xr[4][132];      // per-wave row buffer

  const int tid  = threadIdx.x;
  const int lane = tid & 63;
  const int w    = tid >> 6;

#pragma unroll
  for (int i = 0; i < 16; ++i) {
    int off = i * 1024 + tid * 4;
    *(float4*)&w_lds[off] = *(const float4*)&W[off];
  }
  __syncthreads();

  const float2 bs = *(const float2*)&bias[lane * 2];
  const int nwaves = gridDim.x * 4;

  for (int row = blockIdx.x * 4 + w; row < n; row += nwaves) {
    float2 xv = *(const float2*)&X[(long)row * D + lane * 2];
    *(float2*)&xr[w][lane * 2] = xv;          // wave-private buffer, no barrier
    float acc0 = bs.x, acc1 = bs.y;
#pragma unroll
    for (int k0 = 0; k0 < D; k0 += 4) {
      float4 xb = *(const float4*)&xr[w][k0]; // broadcast
#pragma unroll
      for (int kk = 0; kk < 4; ++kk) {
        float2 wv = *(const float2*)&w_lds[(k0 + kk) * D + lane * 2];
        float xs = f4c(xb, kk);
        acc0 += xs * wv.x;
        acc1 += xs * wv.y;
      }
    }
    u32 packed = (u32)f2bf(acc0) | ((u32)f2bf(acc1) << 16);
    *(u32*)&OutB[(long)row * D + lane * 2] = packed;
  }
}

// ================= MFMA conv: h = node@Ws + agg@Wn + b =================
// fused: gacc += segsum(h) ; node' = relu(LN(h + node)) [bf16, + fp32 on last layer]
__global__ __launch_bounds__(256) void k_conv_mfma(
    const u16* __restrict__ nodeB, const u16* __restrict__ aggB,
    const u16* __restrict__ WsT, const u16* __restrict__ WnT,   // [n][k] bf16
    const float* __restrict__ bias,
    const float* __restrict__ lg, const float* __restrict__ lb,
    const int* __restrict__ batch,
    float* __restrict__ gacc,
    u16* __restrict__ nodeOutB, float* __restrict__ nodeOutF,
    int n)
{
  __shared__ int batch_lds[64];
  const int tid  = threadIdx.x;
  const int lane = tid & 63;
  const int w    = tid >> 6;        // wave 0..3, owns rows w*16..w*16+15
  const int l15  = lane & 15;
  const int g    = lane >> 4;       // 0..3
  const long base = (long)blockIdx.x * 64;

  if (tid < 64) {
    long r = base + tid;
    batch_lds[tid] = batch[r < n ? r : (n - 1)];
  }
  __syncthreads();

  // ---- A fragments: row = l15 within wave tile, k-chunk = g*8 (+32 per kstep)
  long arow  = base + w * 16 + l15;
  long arowc = arow < n ? arow : (n - 1);

  bf16x8 aS[4], aA[4];
#pragma unroll
  for (int ks = 0; ks < 4; ++ks) {
    int k0 = ks * 32 + g * 8;
    aS[ks] = *(const bf16x8*)&nodeB[arowc * D + k0];
    aA[ks] = *(const bf16x8*)&aggB [arowc * D + k0];
  }

  f32x4 acc[8] = {};

#pragma unroll
  for (int f = 0; f < 8; ++f) {
    int nn = f * 16 + l15;
#pragma unroll
    for (int ks = 0; ks < 4; ++ks) {
      int k0 = ks * 32 + g * 8;
      bf16x8 bS = *(const bf16x8*)&WsT[nn * D + k0];
      bf16x8 bA = *(const bf16x8*)&WnT[nn * D + k0];
      acc[f] = __builtin_amdgcn_mfma_f32_16x16x32_bf16(aS[ks], bS, acc[f], 0, 0, 0);
      acc[f] = __builtin_amdgcn_mfma_f32_16x16x32_bf16(aA[ks], bA, acc[f], 0, 0, 0);
    }
  }

  // ---- epilogue params (col = f*16 + l15)
  float bs[8], lgv[8], lbv[8];
#pragma unroll
  for (int f = 0; f < 8; ++f) {
    bs[f]  = bias[f * 16 + l15];
    lgv[f] = lg[f * 16 + l15];
    lbv[f] = lb[f * 16 + l15];
  }

  // acc := h = conv + bias ; output rows: row_local = w*16 + g*4 + r
#pragma unroll
  for (int f = 0; f < 8; ++f)
#pragma unroll
    for (int r = 0; r < 4; ++r) acc[f][r] += bs[f];

  long rowb[4];
  bool valid[4];
#pragma unroll
  for (int r = 0; r < 4; ++r) {
    rowb[r]  = base + w * 16 + g * 4 + r;
    valid[r] = rowb[r] < n;
  }

  // ---- graph segment sum over this wave's 16 rows (batch sorted) ----
  const int wb = w * 16;
  int b_first = batch_lds[wb], b_last = batch_lds[wb + 15];
  if (b_first == b_last) {
#pragma unroll
    for (int f = 0; f < 8; ++f) {
      float ps = 0.f;
#pragma unroll
      for (int r = 0; r < 4; ++r) if (valid[r]) ps += acc[f][r];
      ps += __shfl_xor(ps, 16);
      ps += __shfl_xor(ps, 32);
      if (lane < 16) atomicAdd(&gacc[b_first * D + f * 16 + lane], ps);
    }
  } else {
    int i = 0;
    while (i < 16) {                    // wave-uniform (LDS scalars)
      int bseg = batch_lds[wb + i];
      int j = i + 1;
      while (j < 16 && batch_lds[wb + j] == bseg) ++j;
#pragma unroll
      for (int f = 0; f < 8; ++f) {
        float ps = 0.f;
#pragma unroll
        for (int r = 0; r < 4; ++r) {
          int lr = g * 4 + r;
          if (valid[r] && lr >= i && lr < j) ps += acc[f][r];
        }
        ps += __shfl_xor(ps, 16);
        ps += __shfl_xor(ps, 32);
        if (lane < 16) atomicAdd(&gacc[bseg * D + f * 16 + lane], ps);
      }
      i = j;
    }
  }

  // ---- residual + LN + relu ----
  float xv[8][4];
  float s[4] = {0, 0, 0, 0}, q[4] = {0, 0, 0, 0};
#pragma unroll
  for (int r = 0; r < 4; ++r) {
    long row = valid[r] ? rowb[r] : (n - 1);
#pragma unroll
    for (int f = 0; f < 8; ++f) {
      float nv = bf2f(nodeB[row * D + f * 16 + l15]);
      float x  = acc[f][r] + nv;
      xv[f][r] = x;
      s[r] += x; q[r] += x * x;
    }
  }
#pragma unroll
  for (int r = 0; r < 4; ++r) {
#pragma unroll
    for (int m = 1; m < 16; m <<= 1) {
      s[r] += __shfl_xor(s[r], m);
      q[r] += __shfl_xor(q[r], m);
    }
  }
#pragma unroll
  for (int r = 0; r < 4; ++r) {
    if (!valid[r]) continue;
    float mean = s[r] * (1.f / 128.f);
    float var  = q[r] * (1.f / 128.f) - mean * mean;
    float rs   = rsqrtf(fmaxf(var, 0.f) + 1e-5f);
#pragma unroll
    for (int f = 0; f < 8; ++f) {
      float y = fmaxf((xv[f][r] - mean) * rs * lgv[f] + lbv[f], 0.f);
      nodeOutB[rowb[r] * D + f * 16 + l15] = f2bf(y);
      if (nodeOutF) nodeOutF[rowb[r] * D + f * 16 + l15] = y;
    }
  }
}

// ================= graph LN: graph = LN(LN(gacc + graph)) =================
__global__ void k_ln_graph(const float* __restrict__ gacc,
                           float* __restrict__ graph,
                           const float* __restrict__ lg,
                           const float* __restrict__ lb)
{
  int row  = blockIdx.x;
  int lane = threadIdx.x;
  float2 gv = *(const float2*)&lg[lane * 2];
  float2 bv = *(const float2*)&lb[lane * 2];
  float2 a = *(const float2*)&gacc[row * D + lane * 2];
  float2 p = *(const float2*)&graph[row * D + lane * 2];
  float x0 = a.x + p.x, x1 = a.y + p.y;
#pragma unroll
  for (int pass = 0; pass < 2; ++pass) {
    float s = x0 + x1, q = x0 * x0 + x1 * x1;
#pragma unroll
    for (int m = 1; m < 64; m <<= 1) { s += __shfl_xor(s, m); q += __shfl_xor(q, m); }
    float mean = s * (1.f / 128.f);
    float var  = q * (1.f / 128.f) - mean * mean;
    float rs   = rsqrtf(fmaxf(var, 0.f) + 1e-5f);
    x0 = (x0 - mean) * rs * gv.x + bv.x;
    x1 = (x1 - mean) * rs * gv.y + bv.y;
  }
  float2 o; o.x = x0; o.y = x1;
  *(float2*)&graph[row * D + lane * 2] = o;
}

extern "C" void kernel_launch(void* const* d_in, const int* in_sizes, int n_in,
                              void* d_out, int out_size, void* d_ws, size_t ws_size,
                              hipStream_t stream)
{
  const float* x       = (const float*)d_in[0];
  const int*   edge    = (const int*)d_in[1];
  const int*   batch   = (const int*)d_in[2];
  const float* fc_w    = (const float*)d_in[3];
  const float* fc_b    = (const float*)d_in[4];
  const float* w_self  = (const float*)d_in[5];
  const float* w_neigh = (const float*)d_in[6];
  const float* conv_b  = (const float*)d_in[7];
  const float* ln_g    = (const float*)d_in[8];
  const float* ln_b    = (const float*)d_in[9];

  const int N = in_sizes[0] / D;
  const int E = in_sizes[1] / 2;
  const int* src = edge;
  const int* dst = edge + E;

  // ---- workspace layout ----
  int*   cnt      = (int*)d_ws;                 // N
  int*   rowptr   = cnt + N;                    // N
  int*   cursor   = rowptr + N;                 // N (ends as row-end)
  int*   bsum     = cursor + N;                 // 1024
  int*   csr_src  = bsum + 1024;                // E
  float* invdeg   = (float*)(csr_src + E);      // N
  float* gacc     = invdeg + N;                 // G*D
  float* graphbuf = gacc + NG * D;              // G*D
  // 16B-align the bf16 region
  char*  bfbase   = (char*)(graphbuf + NG * D);
  bfbase = (char*)(((size_t)bfbase + 15) & ~(size_t)15);
  u16*   nodeB    = (u16*)bfbase;               // N*D bf16
  u16*   aggB     = nodeB + (long)N * D;        // N*D bf16
  u16*   wsT      = aggB + (long)N * D;         // 3*128*128 bf16
  u16*   wnT      = wsT + 3 * D * D;            // 3*128*128 bf16

  const int nb = (N + 1023) / 1024;
  const int psize = (N + NPART - 1) / NPART;

  hipMemsetAsync(cnt, 0, (size_t)N * sizeof(int), stream);
  hipMemsetAsync(graphbuf, 0, (size_t)NG * D * sizeof(float), stream);

  // ---- CSR build (once, XCD-partitioned) ----
  k_count<<<2048, 256, 0, stream>>>(dst, cnt, E, psize);
  k_invdeg<<<(N + 255) / 256, 256, 0, stream>>>(cnt, invdeg, N);
  k_blocksum<<<nb, 256, 0, stream>>>(cnt, bsum, N);
  k_scan_bsum<<<1, 1024, 0, stream>>>(bsum, nb);
  k_rowptr<<<nb, 256, 0, stream>>>(cnt, bsum, rowptr, cursor, N);
  k_fill<<<2048, 256, 0, stream>>>(src, dst, cursor, csr_src, E, psize);

  // ---- weight prep (bf16, transposed to [n][k]) ----
  k_wprep<<<192, 256, 0, stream>>>(w_self,  wsT, NL);
  k_wprep<<<192, 256, 0, stream>>>(w_neigh, wnT, NL);

  // ---- input projection: nodeB = bf16(x @ fc_w + fc_b) ----
  k_proj<<<512, 256, 0, stream>>>(x, fc_w, fc_b, nodeB, N);

  const int cblocks = (N + 63) / 64;
  const int ablocks = (N + 15) / 16;
  for (int l = 0; l < NL; ++l) {
    hipMemsetAsync(gacc, 0, (size_t)NG * D * sizeof(float), stream);
    k_aggr<<<ablocks, 256, 0, stream>>>(nodeB, rowptr, cursor, invdeg,
                                        csr_src, aggB, N);
    k_conv_mfma<<<cblocks, 256, 0, stream>>>(
        nodeB, aggB, wsT + (long)l * D * D, wnT + (long)l * D * D,
        conv_b + l * D, ln_g + l * D, ln_b + l * D,
        batch, gacc,
        nodeB, (l == NL - 1) ? (float*)d_out : nullptr, N);
    k_ln_graph<<<NG, 64, 0, stream>>>(gacc, graphbuf, ln_g + l * D, ln_b + l * D);
  }

  // ---- graph output ----
  hipMemcpyAsync((float*)d_out + (long)N * D, graphbuf,
                 (size_t)NG * D * sizeof(float),
                 hipMemcpyDeviceToDevice, stream);
}

// Round 8
// 587.666 us; speedup vs baseline: 18.4025x; 1.0736x over previous
//
#include <hip/hip_runtime.h>

#define D 128
#define NG 64
#define NL 3
#define NPART 8

typedef __attribute__((ext_vector_type(8))) short bf16x8;
typedef __attribute__((ext_vector_type(4))) float f32x4;
typedef unsigned short u16;
typedef unsigned int   u32;

__device__ __forceinline__ u16 f2bf(float x) {   // RNE
  u32 u = __float_as_uint(x);
  return (u16)((u + 0x7FFF + ((u >> 16) & 1)) >> 16);
}
__device__ __forceinline__ float bf2f(u16 b) {
  return __uint_as_float((u32)b << 16);
}

// ================= CSR build (XCD-partitioned by dst range) =================
__global__ void k_count(const int* __restrict__ dst, int* __restrict__ cnt,
                        int E, int psize) {
  const int myp = blockIdx.x & (NPART - 1);
  const int lo  = myp * psize, hi = lo + psize;
  const int tpp = (gridDim.x / NPART) * blockDim.x;        // threads per partition
  int i = (blockIdx.x >> 3) * blockDim.x + threadIdx.x;
  for (; i < E; i += tpp) {
    int t = dst[i];
    if (t >= lo && t < hi) atomicAdd(&cnt[t], 1);
  }
}

__global__ void k_fill(const int* __restrict__ src, const int* __restrict__ dst,
                       int* __restrict__ cursor, int* __restrict__ csr_src,
                       int E, int psize) {
  const int myp = blockIdx.x & (NPART - 1);
  const int lo  = myp * psize, hi = lo + psize;
  const int tpp = (gridDim.x / NPART) * blockDim.x;
  int i = (blockIdx.x >> 3) * blockDim.x + threadIdx.x;
  for (; i < E; i += tpp) {
    int t = dst[i];
    int s = src[i];                                        // coalesced, L3-served
    if (t >= lo && t < hi) {
      int pos = atomicAdd(&cursor[t], 1);
      csr_src[pos] = s;
    }
  }
}

__global__ void k_invdeg(const int* __restrict__ cnt, float* __restrict__ invdeg, int n) {
  int i = blockIdx.x * blockDim.x + threadIdx.x;
  if (i < n) invdeg[i] = 1.0f / (float)max(cnt[i], 1);
}

__global__ void k_blocksum(const int* __restrict__ cnt, int* __restrict__ bsum, int n) {
  int b = blockIdx.x, t = threadIdx.x;
  int base = b * 1024 + t * 4;
  int s = 0;
#pragma unroll
  for (int j = 0; j < 4; ++j) if (base + j < n) s += cnt[base + j];
  int lane = t & 63, w = t >> 6;
#pragma unroll
  for (int m = 1; m < 64; m <<= 1) s += __shfl_xor(s, m);
  __shared__ int ws[4];
  if (lane == 0) ws[w] = s;
  __syncthreads();
  if (t == 0) bsum[b] = ws[0] + ws[1] + ws[2] + ws[3];
}

__global__ void k_scan_bsum(int* __restrict__ bsum, int nb) {
  __shared__ int s[1024];
  int t = threadIdx.x;
  int v = t < nb ? bsum[t] : 0;
  s[t] = v;
  __syncthreads();
  for (int off = 1; off < 1024; off <<= 1) {
    int x = (t >= off) ? s[t - off] : 0;
    __syncthreads();
    s[t] += x;
    __syncthreads();
  }
  if (t < nb) bsum[t] = s[t] - v;   // exclusive
}

__global__ void k_rowptr(const int* __restrict__ cnt, const int* __restrict__ bsum,
                         int* __restrict__ rowptr, int* __restrict__ cursor, int n) {
  int b = blockIdx.x, t = threadIdx.x;
  int base = b * 1024 + t * 4;
  int v0 = 0, v1 = 0, v2 = 0, v3 = 0;
  if (base + 0 < n) v0 = cnt[base + 0];
  if (base + 1 < n) v1 = cnt[base + 1];
  if (base + 2 < n) v2 = cnt[base + 2];
  if (base + 3 < n) v3 = cnt[base + 3];
  int ts = v0 + v1 + v2 + v3;
  int lane = t & 63, w = t >> 6;
  int incl = ts;
#pragma unroll
  for (int m = 1; m < 64; m <<= 1) {
    int o = __shfl_up(incl, m);
    if (lane >= m) incl += o;
  }
  __shared__ int wsum[4];
  if (lane == 63) wsum[w] = incl;
  __syncthreads();
  int woff = 0;
  for (int i = 0; i < w; ++i) woff += wsum[i];
  int run = incl - ts + woff + bsum[b];
  if (base + 0 < n) { rowptr[base + 0] = run; cursor[base + 0] = run; run += v0; }
  if (base + 1 < n) { rowptr[base + 1] = run; cursor[base + 1] = run; run += v1; }
  if (base + 2 < n) { rowptr[base + 2] = run; cursor[base + 2] = run; run += v2; }
  if (base + 3 < n) { rowptr[base + 3] = run; cursor[base + 3] = run; run += v3; }
}

// ================= weight prep: Wt[m][n][k] = bf16(W[m][k][n]) =================
__global__ void k_wprep(const float* __restrict__ W, u16* __restrict__ Wt, int nmats) {
  long idx = (long)blockIdx.x * blockDim.x + threadIdx.x;
  long total = (long)nmats * 16384;
  long stride = (long)gridDim.x * blockDim.x;
  for (; idx < total; idx += stride) {
    long m = idx >> 14;
    int o = (int)(idx & 16383);
    int nn = o >> 7, k = o & 127;
    Wt[idx] = f2bf(W[m * 16384 + k * 128 + nn]);
  }
}

// ================= aggregation: aggB[i] = bf16(mean_{e: dst=i} node[src[e]]) =========
// 16-lane group per node (4 nodes/wave); lane reads bf16x8 (16B) chunk of each row.
// CSR indices preloaded 16-at-a-time + shfl broadcast; 8 independent gathers in flight.
__global__ void k_aggr(const u16* __restrict__ nodeB,
                       const int* __restrict__ rowptr, const int* __restrict__ rowend,
                       const float* __restrict__ invdeg,
                       const int* __restrict__ csr_src,
                       u16* __restrict__ aggB, int n) {
  const int tid  = threadIdx.x;
  const int lane = tid & 63;
  const int l15  = lane & 15;
  const int g    = lane >> 4;                               // group 0..3
  const int wav  = (blockIdx.x * blockDim.x + tid) >> 6;
  const int node = wav * 4 + g;
  if (node >= n) return;

  const int s0 = rowptr[node];
  const int nk = rowend[node] - s0;
  const long off = (long)l15 * 8;                           // 8 bf16 per lane

  float acc[8] = {};

  for (int kb = 0; kb < nk; kb += 16) {
    const int rem = min(16, nk - kb);
    int myidx = (l15 < rem) ? csr_src[s0 + kb + l15] : 0;   // 64B coalesced per group
    int kk = 0;
    for (; kk + 8 <= rem; kk += 8) {
      bf16x8 v[8];
#pragma unroll
      for (int j = 0; j < 8; ++j) {
        int s = __shfl(myidx, (g << 4) + kk + j);           // in-register broadcast
        v[j] = *(const bf16x8*)&nodeB[(long)s * D + off];   // 8 independent gathers
      }
#pragma unroll
      for (int j = 0; j < 8; ++j)
#pragma unroll
        for (int e = 0; e < 8; ++e)
          acc[e] += bf2f((u16)v[j][e]);
    }
    for (; kk + 4 <= rem; kk += 4) {
      bf16x8 v[4];
#pragma unroll
      for (int j = 0; j < 4; ++j) {
        int s = __shfl(myidx, (g << 4) + kk + j);
        v[j] = *(const bf16x8*)&nodeB[(long)s * D + off];
      }
#pragma unroll
      for (int j = 0; j < 4; ++j)
#pragma unroll
        for (int e = 0; e < 8; ++e)
          acc[e] += bf2f((u16)v[j][e]);
    }
    for (; kk < rem; ++kk) {
      int s = __shfl(myidx, (g << 4) + kk);
      bf16x8 v = *(const bf16x8*)&nodeB[(long)s * D + off];
#pragma unroll
      for (int e = 0; e < 8; ++e) acc[e] += bf2f((u16)v[e]);
    }
  }

  const float sc = invdeg[node];
  bf16x8 ov;
#pragma unroll
  for (int e = 0; e < 8; ++e) ov[e] = (short)f2bf(acc[e] * sc);
  *(bf16x8*)&aggB[(long)node * D + off] = ov;               // 16B coalesced store
}

// ================= MFMA projection: nodeB = bf16(X @ W + b) =================
// Same tile structure as k_conv_mfma; x converted fp32->bf16 in-register, no LDS.
__global__ __launch_bounds__(256) void k_proj_mfma(
    const float* __restrict__ X, const u16* __restrict__ WT,   // [n][k] bf16
    const float* __restrict__ bias, u16* __restrict__ OutB, int n)
{
  const int tid  = threadIdx.x;
  const int lane = tid & 63;
  const int w    = tid >> 6;        // wave 0..3, owns rows w*16..w*16+15
  const int l15  = lane & 15;
  const int g    = lane >> 4;       // 0..3
  const long base = (long)blockIdx.x * 64;

  long arow  = base + w * 16 + l15;
  long arowc = arow < n ? arow : (n - 1);

  // A fragments: 8 consecutive fp32 -> bf16x8, k-chunk = g*8 (+32 per kstep)
  bf16x8 aX[4];
#pragma unroll
  for (int ks = 0; ks < 4; ++ks) {
    int k0 = ks * 32 + g * 8;
    float4 x0 = *(const float4*)&X[arowc * D + k0];
    float4 x1 = *(const float4*)&X[arowc * D + k0 + 4];
    bf16x8 a;
    a[0] = (short)f2bf(x0.x); a[1] = (short)f2bf(x0.y);
    a[2] = (short)f2bf(x0.z); a[3] = (short)f2bf(x0.w);
    a[4] = (short)f2bf(x1.x); a[5] = (short)f2bf(x1.y);
    a[6] = (short)f2bf(x1.z); a[7] = (short)f2bf(x1.w);
    aX[ks] = a;
  }

  f32x4 acc[8] = {};
#pragma unroll
  for (int f = 0; f < 8; ++f) {
    int nn = f * 16 + l15;
#pragma unroll
    for (int ks = 0; ks < 4; ++ks) {
      int k0 = ks * 32 + g * 8;
      bf16x8 bW = *(const bf16x8*)&WT[nn * D + k0];
      acc[f] = __builtin_amdgcn_mfma_f32_16x16x32_bf16(aX[ks], bW, acc[f], 0, 0, 0);
    }
  }

  float bs[8];
#pragma unroll
  for (int f = 0; f < 8; ++f) bs[f] = bias[f * 16 + l15];

#pragma unroll
  for (int r = 0; r < 4; ++r) {
    long row = base + w * 16 + g * 4 + r;
    if (row >= n) continue;
#pragma unroll
    for (int f = 0; f < 8; ++f)
      OutB[row * D + f * 16 + l15] = f2bf(acc[f][r] + bs[f]);
  }
}

// ================= MFMA conv: h = node@Ws + agg@Wn + b =================
// fused: gacc += segsum(h) ; node' = relu(LN(h + node)) [bf16, + fp32 on last layer]
__global__ __launch_bounds__(256) void k_conv_mfma(
    const u16* __restrict__ nodeB, const u16* __restrict__ aggB,
    const u16* __restrict__ WsT, const u16* __restrict__ WnT,   // [n][k] bf16
    const float* __restrict__ bias,
    const float* __restrict__ lg, const float* __restrict__ lb,
    const int* __restrict__ batch,
    float* __restrict__ gacc,
    u16* __restrict__ nodeOutB, float* __restrict__ nodeOutF,
    int n)
{
  __shared__ int batch_lds[64];
  const int tid  = threadIdx.x;
  const int lane = tid & 63;
  const int w    = tid >> 6;        // wave 0..3, owns rows w*16..w*16+15
  const int l15  = lane & 15;
  const int g    = lane >> 4;       // 0..3
  const long base = (long)blockIdx.x * 64;

  if (tid < 64) {
    long r = base + tid;
    batch_lds[tid] = batch[r < n ? r : (n - 1)];
  }
  __syncthreads();

  // ---- A fragments: row = l15 within wave tile, k-chunk = g*8 (+32 per kstep)
  long arow  = base + w * 16 + l15;
  long arowc = arow < n ? arow : (n - 1);

  bf16x8 aS[4], aA[4];
#pragma unroll
  for (int ks = 0; ks < 4; ++ks) {
    int k0 = ks * 32 + g * 8;
    aS[ks] = *(const bf16x8*)&nodeB[arowc * D + k0];
    aA[ks] = *(const bf16x8*)&aggB [arowc * D + k0];
  }

  f32x4 acc[8] = {};

#pragma unroll
  for (int f = 0; f < 8; ++f) {
    int nn = f * 16 + l15;
#pragma unroll
    for (int ks = 0; ks < 4; ++ks) {
      int k0 = ks * 32 + g * 8;
      bf16x8 bS = *(const bf16x8*)&WsT[nn * D + k0];
      bf16x8 bA = *(const bf16x8*)&WnT[nn * D + k0];
      acc[f] = __builtin_amdgcn_mfma_f32_16x16x32_bf16(aS[ks], bS, acc[f], 0, 0, 0);
      acc[f] = __builtin_amdgcn_mfma_f32_16x16x32_bf16(aA[ks], bA, acc[f], 0, 0, 0);
    }
  }

  // ---- epilogue params (col = f*16 + l15)
  float bs[8], lgv[8], lbv[8];
#pragma unroll
  for (int f = 0; f < 8; ++f) {
    bs[f]  = bias[f * 16 + l15];
    lgv[f] = lg[f * 16 + l15];
    lbv[f] = lb[f * 16 + l15];
  }

  // acc := h = conv + bias ; output rows: row_local = w*16 + g*4 + r
#pragma unroll
  for (int f = 0; f < 8; ++f)
#pragma unroll
    for (int r = 0; r < 4; ++r) acc[f][r] += bs[f];

  long rowb[4];
  bool valid[4];
#pragma unroll
  for (int r = 0; r < 4; ++r) {
    rowb[r]  = base + w * 16 + g * 4 + r;
    valid[r] = rowb[r] < n;
  }

  // ---- graph segment sum over this wave's 16 rows (batch sorted) ----
  const int wb = w * 16;
  int b_first = batch_lds[wb], b_last = batch_lds[wb + 15];
  if (b_first == b_last) {
#pragma unroll
    for (int f = 0; f < 8; ++f) {
      float ps = 0.f;
#pragma unroll
      for (int r = 0; r < 4; ++r) if (valid[r]) ps += acc[f][r];
      ps += __shfl_xor(ps, 16);
      ps += __shfl_xor(ps, 32);
      if (lane < 16) atomicAdd(&gacc[b_first * D + f * 16 + lane], ps);
    }
  } else {
    int i = 0;
    while (i < 16) {                    // wave-uniform (LDS scalars)
      int bseg = batch_lds[wb + i];
      int j = i + 1;
      while (j < 16 && batch_lds[wb + j] == bseg) ++j;
#pragma unroll
      for (int f = 0; f < 8; ++f) {
        float ps = 0.f;
#pragma unroll
        for (int r = 0; r < 4; ++r) {
          int lr = g * 4 + r;
          if (valid[r] && lr >= i && lr < j) ps += acc[f][r];
        }
        ps += __shfl_xor(ps, 16);
        ps += __shfl_xor(ps, 32);
        if (lane < 16) atomicAdd(&gacc[bseg * D + f * 16 + lane], ps);
      }
      i = j;
    }
  }

  // ---- residual + LN + relu ----
  float xv[8][4];
  float s[4] = {0, 0, 0, 0}, q[4] = {0, 0, 0, 0};
#pragma unroll
  for (int r = 0; r < 4; ++r) {
    long row = valid[r] ? rowb[r] : (n - 1);
#pragma unroll
    for (int f = 0; f < 8; ++f) {
      float nv = bf2f(nodeB[row * D + f * 16 + l15]);
      float x  = acc[f][r] + nv;
      xv[f][r] = x;
      s[r] += x; q[r] += x * x;
    }
  }
#pragma unroll
  for (int r = 0; r < 4; ++r) {
#pragma unroll
    for (int m = 1; m < 16; m <<= 1) {
      s[r] += __shfl_xor(s[r], m);
      q[r] += __shfl_xor(q[r], m);
    }
  }
#pragma unroll
  for (int r = 0; r < 4; ++r) {
    if (!valid[r]) continue;
    float mean = s[r] * (1.f / 128.f);
    float var  = q[r] * (1.f / 128.f) - mean * mean;
    float rs   = rsqrtf(fmaxf(var, 0.f) + 1e-5f);
#pragma unroll
    for (int f = 0; f < 8; ++f) {
      float y = fmaxf((xv[f][r] - mean) * rs * lgv[f] + lbv[f], 0.f);
      nodeOutB[rowb[r] * D + f * 16 + l15] = f2bf(y);
      if (nodeOutF) nodeOutF[rowb[r] * D + f * 16 + l15] = y;
    }
  }
}

// ================= graph LN: graph = LN(LN(gacc + graph)) =================
__global__ void k_ln_graph(const float* __restrict__ gacc,
                           float* __restrict__ graph,
                           const float* __restrict__ lg,
                           const float* __restrict__ lb)
{
  int row  = blockIdx.x;
  int lane = threadIdx.x;
  float2 gv = *(const float2*)&lg[lane * 2];
  float2 bv = *(const float2*)&lb[lane * 2];
  float2 a = *(const float2*)&gacc[row * D + lane * 2];
  float2 p = *(const float2*)&graph[row * D + lane * 2];
  float x0 = a.x + p.x, x1 = a.y + p.y;
#pragma unroll
  for (int pass = 0; pass < 2; ++pass) {
    float s = x0 + x1, q = x0 * x0 + x1 * x1;
#pragma unroll
    for (int m = 1; m < 64; m <<= 1) { s += __shfl_xor(s, m); q += __shfl_xor(q, m); }
    float mean = s * (1.f / 128.f);
    float var  = q * (1.f / 128.f) - mean * mean;
    float rs   = rsqrtf(fmaxf(var, 0.f) + 1e-5f);
    x0 = (x0 - mean) * rs * gv.x + bv.x;
    x1 = (x1 - mean) * rs * gv.y + bv.y;
  }
  float2 o; o.x = x0; o.y = x1;
  *(float2*)&graph[row * D + lane * 2] = o;
}

extern "C" void kernel_launch(void* const* d_in, const int* in_sizes, int n_in,
                              void* d_out, int out_size, void* d_ws, size_t ws_size,
                              hipStream_t stream)
{
  const float* x       = (const float*)d_in[0];
  const int*   edge    = (const int*)d_in[1];
  const int*   batch   = (const int*)d_in[2];
  const float* fc_w    = (const float*)d_in[3];
  const float* fc_b    = (const float*)d_in[4];
  const float* w_self  = (const float*)d_in[5];
  const float* w_neigh = (const float*)d_in[6];
  const float* conv_b  = (const float*)d_in[7];
  const float* ln_g    = (const float*)d_in[8];
  const float* ln_b    = (const float*)d_in[9];

  const int N = in_sizes[0] / D;
  const int E = in_sizes[1] / 2;
  const int* src = edge;
  const int* dst = edge + E;

  // ---- workspace layout ----
  int*   cnt      = (int*)d_ws;                 // N
  int*   rowptr   = cnt + N;                    // N
  int*   cursor   = rowptr + N;                 // N (ends as row-end)
  int*   bsum     = cursor + N;                 // 1024
  int*   csr_src  = bsum + 1024;                // E
  float* invdeg   = (float*)(csr_src + E);      // N
  float* gacc     = invdeg + N;                 // G*D
  float* graphbuf = gacc + NG * D;              // G*D
  // 16B-align the bf16 region
  char*  bfbase   = (char*)(graphbuf + NG * D);
  bfbase = (char*)(((size_t)bfbase + 15) & ~(size_t)15);
  u16*   nodeB    = (u16*)bfbase;               // N*D bf16
  u16*   aggB     = nodeB + (long)N * D;        // N*D bf16
  u16*   wsT      = aggB + (long)N * D;         // 3*128*128 bf16
  u16*   wnT      = wsT + 3 * D * D;            // 3*128*128 bf16
  u16*   fcT      = wnT + 3 * D * D;            // 128*128 bf16

  const int nb = (N + 1023) / 1024;
  const int psize = (N + NPART - 1) / NPART;

  hipMemsetAsync(cnt, 0, (size_t)N * sizeof(int), stream);
  hipMemsetAsync(graphbuf, 0, (size_t)NG * D * sizeof(float), stream);

  // ---- CSR build (once, XCD-partitioned) ----
  k_count<<<2048, 256, 0, stream>>>(dst, cnt, E, psize);
  k_invdeg<<<(N + 255) / 256, 256, 0, stream>>>(cnt, invdeg, N);
  k_blocksum<<<nb, 256, 0, stream>>>(cnt, bsum, N);
  k_scan_bsum<<<1, 1024, 0, stream>>>(bsum, nb);
  k_rowptr<<<nb, 256, 0, stream>>>(cnt, bsum, rowptr, cursor, N);
  k_fill<<<2048, 256, 0, stream>>>(src, dst, cursor, csr_src, E, psize);

  // ---- weight prep (bf16, transposed to [n][k]) ----
  k_wprep<<<192, 256, 0, stream>>>(w_self,  wsT, NL);
  k_wprep<<<192, 256, 0, stream>>>(w_neigh, wnT, NL);
  k_wprep<<<64, 256, 0, stream>>>(fc_w, fcT, 1);

  // ---- input projection: nodeB = bf16(x @ fc_w + fc_b), MFMA ----
  const int cblocks = (N + 63) / 64;
  k_proj_mfma<<<cblocks, 256, 0, stream>>>(x, fcT, fc_b, nodeB, N);

  const int ablocks = (N + 15) / 16;
  for (int l = 0; l < NL; ++l) {
    hipMemsetAsync(gacc, 0, (size_t)NG * D * sizeof(float), stream);
    k_aggr<<<ablocks, 256, 0, stream>>>(nodeB, rowptr, cursor, invdeg,
                                        csr_src, aggB, N);
    k_conv_mfma<<<cblocks, 256, 0, stream>>>(
        nodeB, aggB, wsT + (long)l * D * D, wnT + (long)l * D * D,
        conv_b + l * D, ln_g + l * D, ln_b + l * D,
        batch, gacc,
        nodeB, (l == NL - 1) ? (float*)d_out : nullptr, N);
    k_ln_graph<<<NG, 64, 0, stream>>>(gacc, graphbuf, ln_g + l * D, ln_b + l * D);
  }

  // ---- graph output ----
  hipMemcpyAsync((float*)d_out + (long)N * D, graphbuf,
                 (size_t)NG * D * sizeof(float),
                 hipMemcpyDeviceToDevice, stream);
}